// Round 1
// 717.453 us; speedup vs baseline: 1.2448x; 1.2448x over previous
//
#include <hip/hip_runtime.h>
#include <hip/hip_bf16.h>

#define N_USER 200000
#define N_ITEM 100000
#define N_NODES 300000
#define EMB 80
#define FEAT 16
#define NL 3
#define NNZ 1000000
#define BATCH 4096
#define OUTW 320

typedef __bf16 bf16x8 __attribute__((ext_vector_type(8)));
typedef float f32x4 __attribute__((ext_vector_type(4)));

__device__ __forceinline__ unsigned short f2bf(float f){
  union { float f; unsigned int i; } x; x.f = f;
  unsigned int i = x.i;
  unsigned int r = i + 0x7fff + ((i >> 16) & 1u);
  return (unsigned short)(r >> 16);
}

// ---- diagnostic fill ----
__global__ void k_fill(float* out, int n, float v){
  int i = blockIdx.x * blockDim.x + threadIdx.x;
  if (i < n) out[i] = v;
}

// ---- winner: last write wins for duplicate u_id ----
__global__ void k_winner(const int* __restrict__ u_id, int* __restrict__ winner){
  int b = blockIdx.x * blockDim.x + threadIdx.x;
  if (b >= BATCH) return;
  atomicMax(&winner[u_id[b]], b);
}

// ---- E = concat(user_tab, item_tab), float4 ----
__global__ void k_copy4(const float4* __restrict__ user_tab, const float4* __restrict__ item_tab,
                        float4* __restrict__ E){
  int idx = blockIdx.x * blockDim.x + threadIdx.x;
  if (idx >= N_NODES*EMB/4) return;
  E[idx] = (idx < N_USER*EMB/4) ? user_tab[idx] : item_tab[idx - N_USER*EMB/4];
}

// ---- blended scatter: E[u_id[b]] = 0.5*(user_tab[u]+feat[b]) for winning b ----
__global__ void k_scatter_blend(const int* __restrict__ u_id, const int* __restrict__ winner,
                        const int* __restrict__ age, const int* __restrict__ sex,
                        const int* __restrict__ month, const int* __restrict__ day,
                        const int* __restrict__ dow,
                        const float* __restrict__ user_tab,
                        const float* __restrict__ age_tab, const float* __restrict__ sex_tab,
                        const float* __restrict__ month_tab, const float* __restrict__ day_tab,
                        const float* __restrict__ dow_tab,
                        float* __restrict__ E){
  int idx = blockIdx.x * blockDim.x + threadIdx.x;
  if (idx >= BATCH*EMB) return;
  int b = idx / EMB;
  int c = idx - b*EMB;
  int u = u_id[b];
  if (winner[u] != b) return;
  int t = c >> 4, cc = c & 15;
  int key; const float* tab;
  switch (t){
    case 0: key = age[b];   tab = age_tab;   break;
    case 1: key = sex[b];   tab = sex_tab;   break;
    case 2: key = month[b]; tab = month_tab; break;
    case 3: key = day[b];   tab = day_tab;   break;
    default: key = dow[b];  tab = dow_tab;   break;
  }
  float f = tab[key*FEAT + cc];
  E[(size_t)u*EMB + c] = 0.5f * user_tab[(size_t)u*EMB + c] + 0.5f * f;
}

// ---- prep: Wt[i][n][k] = stacked [W1;W2]^T (bf16, n-major), biasf = 2*b1+b2 ----
__global__ void k_prep(const float* __restrict__ W1, const float* __restrict__ W2,
                       const float* __restrict__ b1, const float* __restrict__ b2,
                       unsigned short* __restrict__ Wt, float* __restrict__ biasf){
  int idx = blockIdx.x * blockDim.x + threadIdx.x;
  if (idx < NL*EMB*160){
    int i = idx / (EMB*160);
    int rem = idx - i*(EMB*160);
    int n = rem / 160;
    int k = rem - n*160;
    float v = (k < EMB) ? W1[i*EMB*EMB + k*EMB + n] : W2[i*EMB*EMB + (k-EMB)*EMB + n];
    Wt[idx] = f2bf(v);
  } else if (idx < NL*EMB*160 + NL*EMB){
    int t = idx - NL*EMB*160;
    biasf[t] = 2.0f * b1[t] + b2[t];
  }
}

// ================= CSR build =================
__global__ void k_hist(const int* __restrict__ rows, int* __restrict__ cnt){
  int e = blockIdx.x * blockDim.x + threadIdx.x;
  if (e < NNZ) atomicAdd(&cnt[rows[e]], 1);
}

#define SCAN_BLK 1024
__global__ void k_scan1(int* __restrict__ cnt, int* __restrict__ bsum){
  __shared__ int s[256];
  int tid = threadIdx.x;
  int base = blockIdx.x * SCAN_BLK + tid*4;
  int v[4]; int sum = 0;
  #pragma unroll
  for (int j = 0; j < 4; j++){
    int i = base + j;
    v[j] = (i < N_NODES) ? cnt[i] : 0;
    sum += v[j];
  }
  s[tid] = sum; __syncthreads();
  int own = sum;
  for (int d = 1; d < 256; d <<= 1){
    int t = (tid >= d) ? s[tid-d] : 0;
    __syncthreads();
    s[tid] += t;
    __syncthreads();
  }
  int excl = s[tid] - own;
  if (tid == 0) bsum[blockIdx.x] = s[255];
  int run = excl;
  #pragma unroll
  for (int j = 0; j < 4; j++){
    int i = base + j;
    if (i < N_NODES) cnt[i] = run;
    run += v[j];
  }
}

#define NSCAN_BLOCKS ((N_NODES + SCAN_BLK - 1)/SCAN_BLK)   // 293
__global__ void k_scan2(int* __restrict__ bsum){
  __shared__ int s[512];
  int tid = threadIdx.x;
  int v = (tid < NSCAN_BLOCKS) ? bsum[tid] : 0;
  s[tid] = v; __syncthreads();
  for (int d = 1; d < 512; d <<= 1){
    int t = (tid >= d) ? s[tid-d] : 0;
    __syncthreads();
    s[tid] += t;
    __syncthreads();
  }
  if (tid < NSCAN_BLOCKS) bsum[tid] = s[tid] - v;
}

__global__ void k_scan3(int* __restrict__ rowptr, const int* __restrict__ bsum,
                        int* __restrict__ cursor){
  int i = blockIdx.x * blockDim.x + threadIdx.x;
  if (i >= N_NODES) return;
  int v = rowptr[i] + bsum[i >> 10];
  rowptr[i] = v;
  cursor[i] = v;
  if (i == 0) rowptr[N_NODES] = NNZ;
}

// edges[pos] = {col, bitcast(val)} — one 8B store instead of two 4B scatters
__global__ void k_scatter_edges(const int* __restrict__ rows, const int* __restrict__ cols,
                                const float* __restrict__ vals,
                                int* __restrict__ cursor,
                                int2* __restrict__ edges){
  int e = blockIdx.x * blockDim.x + threadIdx.x;
  if (e >= NNZ) return;
  int r = rows[e];
  int pos = atomicAdd(&cursor[r], 1);
  int2 ed; ed.x = cols[e]; ed.y = __float_as_int(vals[e]);
  edges[pos] = ed;
}

// ==== fused layer v3: 4-wide batched gathers in phase 1 (break the latency chain) ====
#define LE_PAD 84   // floats; 336 B row stride -> 2-way bank alias on b128 reads (free)
__launch_bounds__(256)
__global__ void k_fused2(const float* __restrict__ Ein, float* __restrict__ Eout,
                         const int* __restrict__ rowptr, const int2* __restrict__ edges,
                         const unsigned short* __restrict__ Wt, const float* __restrict__ biasf){
  __shared__ float le[64 * LE_PAD];   // 21504 B -> 7 blocks/CU
  int tid = threadIdx.x;
  long row0 = (long)blockIdx.x * 64;

  int lane = tid & 63;
  int wave = tid >> 6;
  int m = lane & 15;
  int quad = lane >> 4;

  // phase 1: CSR SpMM rows -> LDS (20 float4-lanes per row)
  // 5 slots/thread; rowptr for all slots hoisted; edges processed 4-wide with
  // clamped unconditional loads so 4 edge-loads then 4 gathers are in flight at once.
  int s_[5], e_[5], lr_[5], q_[5];
  #pragma unroll
  for (int k = 0; k < 5; k++){
    int u = tid + k*256;
    int lr = u / 20;
    lr_[k] = lr; q_[k] = u - lr*20;
    long r = row0 + lr;
    if (r < N_NODES){ s_[k] = rowptr[r]; e_[k] = rowptr[r+1]; }
    else            { s_[k] = 0;         e_[k] = 0; }
  }

  #pragma unroll
  for (int k = 0; k < 5; k++){
    const float* eb = Ein + q_[k]*4;
    f32x4 acc4 = {0.f,0.f,0.f,0.f};
    int end = e_[k];
    int ilast = end - 1;
    for (int i = s_[k]; i < end; i += 4){
      int rem = end - i;
      int i1 = min(i+1, ilast);
      int i2 = min(i+2, ilast);
      int i3 = min(i+3, ilast);
      int2 ed0 = edges[i];
      int2 ed1 = edges[i1];
      int2 ed2 = edges[i2];
      int2 ed3 = edges[i3];
      float v0 = __int_as_float(ed0.y);
      float v1 = (rem > 1) ? __int_as_float(ed1.y) : 0.f;
      float v2 = (rem > 2) ? __int_as_float(ed2.y) : 0.f;
      float v3 = (rem > 3) ? __int_as_float(ed3.y) : 0.f;
      float4 g0 = *(const float4*)(eb + (size_t)ed0.x*EMB);
      float4 g1 = *(const float4*)(eb + (size_t)ed1.x*EMB);
      float4 g2 = *(const float4*)(eb + (size_t)ed2.x*EMB);
      float4 g3 = *(const float4*)(eb + (size_t)ed3.x*EMB);
      acc4.x += v0*g0.x + v1*g1.x + v2*g2.x + v3*g3.x;
      acc4.y += v0*g0.y + v1*g1.y + v2*g2.y + v3*g3.y;
      acc4.z += v0*g0.z + v1*g1.z + v2*g2.z + v3*g3.z;
      acc4.w += v0*g0.w + v1*g1.w + v2*g2.w + v3*g3.w;
    }
    *(f32x4*)(le + lr_[k]*LE_PAD + q_[k]*4) = acc4;
  }

  // B fragments (Wt n-major) — loaded AFTER phase 1 so the 50 VGPRs aren't live
  // during the gather phase; loads overlap the barrier wait.
  bf16x8 bfrag[5][5];
  #pragma unroll
  for (int nt = 0; nt < 5; nt++)
    #pragma unroll
    for (int kt = 0; kt < 5; kt++)
      bfrag[nt][kt] = *(const bf16x8*)(Wt + (nt*16 + m)*160 + kt*32 + quad*8);

  __syncthreads();

  // phase 2: K=160 GEMM, A-fragments in registers
  int arow = wave*16 + m;                 // LDS row this lane reads
  long rA = row0 + arow;
  const float* erow = Ein + (size_t)(rA < N_NODES ? rA : 0) * EMB;
  const float* lrow = le + arow*LE_PAD;

  f32x4 acc[5];
  #pragma unroll
  for (int nt = 0; nt < 5; nt++) acc[nt] = (f32x4){0.f,0.f,0.f,0.f};

  #pragma unroll
  for (int kt = 0; kt < 5; kt++){
    int k8 = kt*32 + quad*8;              // 8 consecutive k's; never crosses 80 (80%8==0)
    bool addh = (k8 < EMB);
    int c8 = addh ? k8 : k8 - EMB;
    float4 e0 = *(const float4*)(erow + c8);
    float4 e1 = *(const float4*)(erow + c8 + 4);
    float4 l0 = *(const float4*)(lrow + c8);
    float4 l1 = *(const float4*)(lrow + c8 + 4);
    float x0,x1,x2,x3,x4,x5,x6,x7;
    if (addh){
      x0=e0.x+l0.x; x1=e0.y+l0.y; x2=e0.z+l0.z; x3=e0.w+l0.w;
      x4=e1.x+l1.x; x5=e1.y+l1.y; x6=e1.z+l1.z; x7=e1.w+l1.w;
    } else {
      x0=e0.x*l0.x; x1=e0.y*l0.y; x2=e0.z*l0.z; x3=e0.w*l0.w;
      x4=e1.x*l1.x; x5=e1.y*l1.y; x6=e1.z*l1.z; x7=e1.w*l1.w;
    }
    bf16x8 af;
    af[0]=(__bf16)x0; af[1]=(__bf16)x1; af[2]=(__bf16)x2; af[3]=(__bf16)x3;
    af[4]=(__bf16)x4; af[5]=(__bf16)x5; af[6]=(__bf16)x6; af[7]=(__bf16)x7;
    #pragma unroll
    for (int nt = 0; nt < 5; nt++)
      acc[nt] = __builtin_amdgcn_mfma_f32_16x16x32_bf16(af, bfrag[nt][kt], acc[nt], 0, 0, 0);
  }

  // epilogue: C/D layout col=lane&15, row=quad*4+reg
  long rbase = row0 + wave*16 + quad*4;
  #pragma unroll
  for (int nt = 0; nt < 5; nt++){
    int col = nt*16 + m;
    float b = biasf[col];
    #pragma unroll
    for (int i = 0; i < 4; i++){
      long r = rbase + i;
      if (r < N_NODES){
        float v = acc[nt][i] + b;
        Eout[r*EMB + col] = (v > 0.f) ? v : 0.2f * v;
      }
    }
  }
}

// ---- fused gather + row L2 norm (wave per gathered row), fp32 out ----
__global__ void k_gather_wave(const float* __restrict__ E, const int* __restrict__ u_id,
                              const int* __restrict__ pos, const int* __restrict__ neg,
                              float* __restrict__ out, int layer, int do_norm){
  int gw = blockIdx.x * (blockDim.x >> 6) + (threadIdx.x >> 6);
  if (gw >= 3*BATCH) return;
  int lane = threadIdx.x & 63;
  int chunk = gw / BATCH;
  int b = gw - chunk*BATCH;
  int node = (chunk == 0) ? u_id[b] : ((chunk == 1) ? N_USER + pos[b] : N_USER + neg[b]);
  const float* er = E + (size_t)node*EMB;
  float v0 = er[lane];
  float v1 = (lane < EMB-64) ? er[64 + lane] : 0.f;
  float scale = 1.f;
  if (do_norm){
    float ss = v0*v0 + v1*v1;
    #pragma unroll
    for (int s = 32; s > 0; s >>= 1) ss += __shfl_xor(ss, s, 64);
    float nrm = fmaxf(sqrtf(ss), 1e-12f);
    scale = 1.f / nrm;
  }
  float* po = out + (size_t)chunk*BATCH*OUTW + (size_t)b*OUTW + layer*EMB;
  po[lane] = v0 * scale;
  if (lane < EMB-64) po[64 + lane] = v1 * scale;
}

extern "C" void kernel_launch(void* const* d_in, const int* in_sizes, int n_in,
                              void* d_out, int out_size, void* d_ws, size_t ws_size,
                              hipStream_t stream) {
  float* out = (float*)d_out;

  const size_t OFF_E0     = 0;                   // 96,000,000
  const size_t OFF_E1     = 96000000;            // 96,000,000
  const size_t OFF_ROWPTR = 192000000;           // 1,200,640
  const size_t OFF_CURSOR = 193200640;           // 1,200,640
  const size_t OFF_EDGES  = 194401280;           // 8,000,000 (int2 per edge)
  const size_t OFF_BSUM   = 202401280;           // 4,096
  const size_t OFF_WT     = 202405376;           // 76,800
  const size_t OFF_BIAS   = 202482176;           // 1,024
  const size_t OFF_WIN    = 202483200;           // 800,000
  const size_t NEED       = 203283200;

  float code = 0.f;
  if (ws_size < NEED)                      code = 7.f;
  else if (n_in != 22)                     code = 9.f;
  else if (in_sizes[0] != BATCH)           code = 11.f;
  else if (in_sizes[10] != NNZ)            code = 13.f;
  else if (out_size != 3*BATCH*OUTW)       code = 19.f;
  if (code != 0.f){
    k_fill<<<(out_size + 255)/256, 256, 0, stream>>>(out, out_size, code);
    return;
  }

  const int* u_id  = (const int*)d_in[0];
  const int* age   = (const int*)d_in[1];
  const int* sex   = (const int*)d_in[2];
  const int* month = (const int*)d_in[3];
  const int* day   = (const int*)d_in[4];
  const int* dow   = (const int*)d_in[5];
  const int* pos   = (const int*)d_in[6];
  const int* neg   = (const int*)d_in[7];
  const int* lrows = (const int*)d_in[8];
  const int* lcols = (const int*)d_in[9];
  const float* lvals    = (const float*)d_in[10];
  const float* user_tab = (const float*)d_in[11];
  const float* item_tab = (const float*)d_in[12];
  const float* age_tab  = (const float*)d_in[13];
  const float* sex_tab  = (const float*)d_in[14];
  const float* month_tab= (const float*)d_in[15];
  const float* day_tab  = (const float*)d_in[16];
  const float* dow_tab  = (const float*)d_in[17];
  const float* W1 = (const float*)d_in[18];
  const float* b1 = (const float*)d_in[19];
  const float* W2 = (const float*)d_in[20];
  const float* b2 = (const float*)d_in[21];

  char* ws = (char*)d_ws;
  float* E0     = (float*)(ws + OFF_E0);
  float* E1     = (float*)(ws + OFF_E1);
  int* rowptr   = (int*)(ws + OFF_ROWPTR);
  int* cursor   = (int*)(ws + OFF_CURSOR);
  int2* edges   = (int2*)(ws + OFF_EDGES);
  int* bsum     = (int*)(ws + OFF_BSUM);
  unsigned short* Wt = (unsigned short*)(ws + OFF_WT);
  float* biasf  = (float*)(ws + OFF_BIAS);
  int* winner   = (int*)(ws + OFF_WIN);

  // ---- prologue: build E0 ----
  hipMemsetAsync(winner, 0xFF, N_USER*sizeof(int), stream);
  k_winner<<<(BATCH+255)/256, 256, 0, stream>>>(u_id, winner);
  k_copy4<<<(N_NODES*EMB/4+255)/256, 256, 0, stream>>>((const float4*)user_tab, (const float4*)item_tab, (float4*)E0);
  k_scatter_blend<<<(BATCH*EMB+255)/256, 256, 0, stream>>>(u_id, winner, age, sex, month, day, dow,
                                                   user_tab, age_tab, sex_tab, month_tab,
                                                   day_tab, dow_tab, E0);
  k_prep<<<(NL*EMB*160 + NL*EMB + 255)/256, 256, 0, stream>>>(W1, W2, b1, b2, Wt, biasf);

  // ---- CSR build ----
  hipMemsetAsync(rowptr, 0, (N_NODES+1)*sizeof(int), stream);
  k_hist<<<(NNZ+255)/256, 256, 0, stream>>>(lrows, rowptr);
  k_scan1<<<NSCAN_BLOCKS, 256, 0, stream>>>(rowptr, bsum);
  k_scan2<<<1, 512, 0, stream>>>(bsum);
  k_scan3<<<(N_NODES+255)/256, 256, 0, stream>>>(rowptr, bsum, cursor);
  k_scatter_edges<<<(NNZ+255)/256, 256, 0, stream>>>(lrows, lcols, lvals, cursor, edges);

  // layer-0 slice (raw E0)
  k_gather_wave<<<(3*BATCH+3)/4, 256, 0, stream>>>(E0, u_id, pos, neg, out, 0, 0);

  // ---- layers (ping-pong E0 <-> E1) ----
  float* Ein = E0; float* Eout = E1;
  for (int i = 0; i < NL; i++){
    k_fused2<<<(N_NODES+63)/64, 256, 0, stream>>>(Ein, Eout, rowptr, edges,
                                                  Wt + i*EMB*160, biasf + i*EMB);
    k_gather_wave<<<(3*BATCH+3)/4, 256, 0, stream>>>(Eout, u_id, pos, neg, out, i+1, 1);
    float* t = Ein; Ein = Eout; Eout = t;
  }
}

// Round 3
// 665.708 us; speedup vs baseline: 1.3416x; 1.0777x over previous
//
#include <hip/hip_runtime.h>
#include <hip/hip_bf16.h>

#define N_USER 200000
#define N_ITEM 100000
#define N_NODES 300000
#define EMB 80
#define FEAT 16
#define NL 3
#define NNZ 1000000
#define BATCH 4096
#define OUTW 320

typedef __bf16 bf16x8 __attribute__((ext_vector_type(8)));
typedef float f32x4 __attribute__((ext_vector_type(4)));

__device__ __forceinline__ unsigned short f2bf(float f){
  union { float f; unsigned int i; } x; x.f = f;
  unsigned int i = x.i;
  unsigned int r = i + 0x7fff + ((i >> 16) & 1u);
  return (unsigned short)(r >> 16);
}

// ---- diagnostic fill ----
__global__ void k_fill(float* out, int n, float v){
  int i = blockIdx.x * blockDim.x + threadIdx.x;
  if (i < n) out[i] = v;
}

// ---- winner: last write wins for duplicate u_id ----
__global__ void k_winner(const int* __restrict__ u_id, int* __restrict__ winner){
  int b = blockIdx.x * blockDim.x + threadIdx.x;
  if (b >= BATCH) return;
  atomicMax(&winner[u_id[b]], b);
}

// ---- E = concat(user_tab, item_tab), float4 ----
__global__ void k_copy4(const float4* __restrict__ user_tab, const float4* __restrict__ item_tab,
                        float4* __restrict__ E){
  int idx = blockIdx.x * blockDim.x + threadIdx.x;
  if (idx >= N_NODES*EMB/4) return;
  E[idx] = (idx < N_USER*EMB/4) ? user_tab[idx] : item_tab[idx - N_USER*EMB/4];
}

// ---- blended scatter: E[u_id[b]] = 0.5*(user_tab[u]+feat[b]) for winning b ----
__global__ void k_scatter_blend(const int* __restrict__ u_id, const int* __restrict__ winner,
                        const int* __restrict__ age, const int* __restrict__ sex,
                        const int* __restrict__ month, const int* __restrict__ day,
                        const int* __restrict__ dow,
                        const float* __restrict__ user_tab,
                        const float* __restrict__ age_tab, const float* __restrict__ sex_tab,
                        const float* __restrict__ month_tab, const float* __restrict__ day_tab,
                        const float* __restrict__ dow_tab,
                        float* __restrict__ E){
  int idx = blockIdx.x * blockDim.x + threadIdx.x;
  if (idx >= BATCH*EMB) return;
  int b = idx / EMB;
  int c = idx - b*EMB;
  int u = u_id[b];
  if (winner[u] != b) return;
  int t = c >> 4, cc = c & 15;
  int key; const float* tab;
  switch (t){
    case 0: key = age[b];   tab = age_tab;   break;
    case 1: key = sex[b];   tab = sex_tab;   break;
    case 2: key = month[b]; tab = month_tab; break;
    case 3: key = day[b];   tab = day_tab;   break;
    default: key = dow[b];  tab = dow_tab;   break;
  }
  float f = tab[key*FEAT + cc];
  E[(size_t)u*EMB + c] = 0.5f * user_tab[(size_t)u*EMB + c] + 0.5f * f;
}

// ---- prep: Wt[i][n][k] = stacked [W1;W2]^T (bf16, n-major), biasf = 2*b1+b2 ----
__global__ void k_prep(const float* __restrict__ W1, const float* __restrict__ W2,
                       const float* __restrict__ b1, const float* __restrict__ b2,
                       unsigned short* __restrict__ Wt, float* __restrict__ biasf){
  int idx = blockIdx.x * blockDim.x + threadIdx.x;
  if (idx < NL*EMB*160){
    int i = idx / (EMB*160);
    int rem = idx - i*(EMB*160);
    int n = rem / 160;
    int k = rem - n*160;
    float v = (k < EMB) ? W1[i*EMB*EMB + k*EMB + n] : W2[i*EMB*EMB + (k-EMB)*EMB + n];
    Wt[idx] = f2bf(v);
  } else if (idx < NL*EMB*160 + NL*EMB){
    int t = idx - NL*EMB*160;
    biasf[t] = 2.0f * b1[t] + b2[t];
  }
}

// ================= CSR build =================
__global__ void k_hist(const int* __restrict__ rows, int* __restrict__ cnt){
  int e = blockIdx.x * blockDim.x + threadIdx.x;
  if (e < NNZ) atomicAdd(&cnt[rows[e]], 1);
}

#define SCAN_BLK 1024
__global__ void k_scan1(int* __restrict__ cnt, int* __restrict__ bsum){
  __shared__ int s[256];
  int tid = threadIdx.x;
  int base = blockIdx.x * SCAN_BLK + tid*4;
  int v[4]; int sum = 0;
  #pragma unroll
  for (int j = 0; j < 4; j++){
    int i = base + j;
    v[j] = (i < N_NODES) ? cnt[i] : 0;
    sum += v[j];
  }
  s[tid] = sum; __syncthreads();
  int own = sum;
  for (int d = 1; d < 256; d <<= 1){
    int t = (tid >= d) ? s[tid-d] : 0;
    __syncthreads();
    s[tid] += t;
    __syncthreads();
  }
  int excl = s[tid] - own;
  if (tid == 0) bsum[blockIdx.x] = s[255];
  int run = excl;
  #pragma unroll
  for (int j = 0; j < 4; j++){
    int i = base + j;
    if (i < N_NODES) cnt[i] = run;
    run += v[j];
  }
}

#define NSCAN_BLOCKS ((N_NODES + SCAN_BLK - 1)/SCAN_BLK)   // 293
__global__ void k_scan2(int* __restrict__ bsum){
  __shared__ int s[512];
  int tid = threadIdx.x;
  int v = (tid < NSCAN_BLOCKS) ? bsum[tid] : 0;
  s[tid] = v; __syncthreads();
  for (int d = 1; d < 512; d <<= 1){
    int t = (tid >= d) ? s[tid-d] : 0;
    __syncthreads();
    s[tid] += t;
    __syncthreads();
  }
  if (tid < NSCAN_BLOCKS) bsum[tid] = s[tid] - v;
}

__global__ void k_scan3(int* __restrict__ rowptr, const int* __restrict__ bsum,
                        int* __restrict__ cursor){
  int i = blockIdx.x * blockDim.x + threadIdx.x;
  if (i >= N_NODES) return;
  int v = rowptr[i] + bsum[i >> 10];
  rowptr[i] = v;
  cursor[i] = v;
  if (i == 0) rowptr[N_NODES] = NNZ;
}

// edges[pos] = {col, bitcast(val)} — one 8B store instead of two 4B scatters
__global__ void k_scatter_edges(const int* __restrict__ rows, const int* __restrict__ cols,
                                const float* __restrict__ vals,
                                int* __restrict__ cursor,
                                int2* __restrict__ edges){
  int e = blockIdx.x * blockDim.x + threadIdx.x;
  if (e >= NNZ) return;
  int r = rows[e];
  int pos = atomicAdd(&cursor[r], 1);
  int2 ed; ed.x = cols[e]; ed.y = __float_as_int(vals[e]);
  edges[pos] = ed;
}

// ==== fused layer v4: 1 slot/thread phase 1 — 4 threads per row, 20 floats each ====
#define LE_PAD 84   // floats; 336 B row stride -> 2-way bank alias on b128 reads (free)
__launch_bounds__(256)
__global__ void k_fused2(const float* __restrict__ Ein, float* __restrict__ Eout,
                         const int* __restrict__ rowptr, const int2* __restrict__ edges,
                         const unsigned short* __restrict__ Wt, const float* __restrict__ biasf){
  __shared__ float le[64 * LE_PAD];   // 21504 B -> 7 blocks/CU
  int tid = threadIdx.x;
  long row0 = (long)blockIdx.x * 64;

  int lane = tid & 63;
  int wave = tid >> 6;
  int m = lane & 15;
  int quad = lane >> 4;

  // phase 1: CSR SpMM rows -> LDS. Each thread owns ONE slot: row tid>>2,
  // floats (tid&3)*20 .. +20. One dynamic loop per thread (was 5 serial),
  // 4-wide clamped edge unroll: 4 edge loads then 20 independent gathers in flight.
  // The 4 threads of a row share edge loads (same address -> L1 broadcast) and
  // together tile the full 320B gathered row.
  {
    int lr = tid >> 2;
    int qg = tid & 3;
    long r = row0 + lr;
    int s = 0, e = 0;
    if (r < N_NODES){ s = rowptr[r]; e = rowptr[r+1]; }
    const float* eb = Ein + qg*20;
    f32x4 a[5];
    #pragma unroll
    for (int j = 0; j < 5; j++) a[j] = (f32x4){0.f,0.f,0.f,0.f};
    int ilast = e - 1;
    for (int i = s; i < e; i += 4){
      int rem = e - i;
      int2 ed0 = edges[i];
      int2 ed1 = edges[min(i+1, ilast)];
      int2 ed2 = edges[min(i+2, ilast)];
      int2 ed3 = edges[min(i+3, ilast)];
      float v0 = __int_as_float(ed0.y);
      float v1 = (rem > 1) ? __int_as_float(ed1.y) : 0.f;
      float v2 = (rem > 2) ? __int_as_float(ed2.y) : 0.f;
      float v3 = (rem > 3) ? __int_as_float(ed3.y) : 0.f;
      const float* g0 = eb + (size_t)ed0.x*EMB;
      const float* g1 = eb + (size_t)ed1.x*EMB;
      const float* g2 = eb + (size_t)ed2.x*EMB;
      const float* g3 = eb + (size_t)ed3.x*EMB;
      #pragma unroll
      for (int j = 0; j < 5; j++){
        float4 x0 = *(const float4*)(g0 + j*4);
        float4 x1 = *(const float4*)(g1 + j*4);
        float4 x2 = *(const float4*)(g2 + j*4);
        float4 x3 = *(const float4*)(g3 + j*4);
        a[j].x += v0*x0.x + v1*x1.x + v2*x2.x + v3*x3.x;
        a[j].y += v0*x0.y + v1*x1.y + v2*x2.y + v3*x3.y;
        a[j].z += v0*x0.z + v1*x1.z + v2*x2.z + v3*x3.z;
        a[j].w += v0*x0.w + v1*x1.w + v2*x2.w + v3*x3.w;
      }
    }
    float* lp = le + lr*LE_PAD + qg*20;
    #pragma unroll
    for (int j = 0; j < 5; j++) *(f32x4*)(lp + j*4) = a[j];
  }

  // B fragments (Wt n-major) — loaded AFTER phase 1 so the 50 VGPRs aren't live
  // during the gather phase; loads overlap the barrier wait.
  bf16x8 bfrag[5][5];
  #pragma unroll
  for (int nt = 0; nt < 5; nt++)
    #pragma unroll
    for (int kt = 0; kt < 5; kt++)
      bfrag[nt][kt] = *(const bf16x8*)(Wt + (nt*16 + m)*160 + kt*32 + quad*8);

  __syncthreads();

  // phase 2: K=160 GEMM, A-fragments in registers
  int arow = wave*16 + m;                 // LDS row this lane reads
  long rA = row0 + arow;
  const float* erow = Ein + (size_t)(rA < N_NODES ? rA : 0) * EMB;
  const float* lrow = le + arow*LE_PAD;

  f32x4 acc[5];
  #pragma unroll
  for (int nt = 0; nt < 5; nt++) acc[nt] = (f32x4){0.f,0.f,0.f,0.f};

  #pragma unroll
  for (int kt = 0; kt < 5; kt++){
    int k8 = kt*32 + quad*8;              // 8 consecutive k's; never crosses 80 (80%8==0)
    bool addh = (k8 < EMB);
    int c8 = addh ? k8 : k8 - EMB;
    float4 e0 = *(const float4*)(erow + c8);
    float4 e1 = *(const float4*)(erow + c8 + 4);
    float4 l0 = *(const float4*)(lrow + c8);
    float4 l1 = *(const float4*)(lrow + c8 + 4);
    float x0,x1,x2,x3,x4,x5,x6,x7;
    if (addh){
      x0=e0.x+l0.x; x1=e0.y+l0.y; x2=e0.z+l0.z; x3=e0.w+l0.w;
      x4=e1.x+l1.x; x5=e1.y+l1.y; x6=e1.z+l1.z; x7=e1.w+l1.w;
    } else {
      x0=e0.x*l0.x; x1=e0.y*l0.y; x2=e0.z*l0.z; x3=e0.w*l0.w;
      x4=e1.x*l1.x; x5=e1.y*l1.y; x6=e1.z*l1.z; x7=e1.w*l1.w;
    }
    bf16x8 af;
    af[0]=(__bf16)x0; af[1]=(__bf16)x1; af[2]=(__bf16)x2; af[3]=(__bf16)x3;
    af[4]=(__bf16)x4; af[5]=(__bf16)x5; af[6]=(__bf16)x6; af[7]=(__bf16)x7;
    #pragma unroll
    for (int nt = 0; nt < 5; nt++)
      acc[nt] = __builtin_amdgcn_mfma_f32_16x16x32_bf16(af, bfrag[nt][kt], acc[nt], 0, 0, 0);
  }

  // epilogue: C/D layout col=lane&15, row=quad*4+reg
  long rbase = row0 + wave*16 + quad*4;
  #pragma unroll
  for (int nt = 0; nt < 5; nt++){
    int col = nt*16 + m;
    float b = biasf[col];
    #pragma unroll
    for (int i = 0; i < 4; i++){
      long r = rbase + i;
      if (r < N_NODES){
        float v = acc[nt][i] + b;
        Eout[r*EMB + col] = (v > 0.f) ? v : 0.2f * v;
      }
    }
  }
}

// ---- fused gather + row L2 norm (wave per gathered row), fp32 out ----
__global__ void k_gather_wave(const float* __restrict__ E, const int* __restrict__ u_id,
                              const int* __restrict__ pos, const int* __restrict__ neg,
                              float* __restrict__ out, int layer, int do_norm){
  int gw = blockIdx.x * (blockDim.x >> 6) + (threadIdx.x >> 6);
  if (gw >= 3*BATCH) return;
  int lane = threadIdx.x & 63;
  int chunk = gw / BATCH;
  int b = gw - chunk*BATCH;
  int node = (chunk == 0) ? u_id[b] : ((chunk == 1) ? N_USER + pos[b] : N_USER + neg[b]);
  const float* er = E + (size_t)node*EMB;
  float v0 = er[lane];
  float v1 = (lane < EMB-64) ? er[64 + lane] : 0.f;
  float scale = 1.f;
  if (do_norm){
    float ss = v0*v0 + v1*v1;
    #pragma unroll
    for (int s = 32; s > 0; s >>= 1) ss += __shfl_xor(ss, s, 64);
    float nrm = fmaxf(sqrtf(ss), 1e-12f);
    scale = 1.f / nrm;
  }
  float* po = out + (size_t)chunk*BATCH*OUTW + (size_t)b*OUTW + layer*EMB;
  po[lane] = v0 * scale;
  if (lane < EMB-64) po[64 + lane] = v1 * scale;
}

extern "C" void kernel_launch(void* const* d_in, const int* in_sizes, int n_in,
                              void* d_out, int out_size, void* d_ws, size_t ws_size,
                              hipStream_t stream) {
  float* out = (float*)d_out;

  const size_t OFF_E0     = 0;                   // 96,000,000
  const size_t OFF_E1     = 96000000;            // 96,000,000
  const size_t OFF_ROWPTR = 192000000;           // 1,200,640
  const size_t OFF_CURSOR = 193200640;           // 1,200,640
  const size_t OFF_EDGES  = 194401280;           // 8,000,000 (int2 per edge)
  const size_t OFF_BSUM   = 202401280;           // 4,096
  const size_t OFF_WT     = 202405376;           // 76,800
  const size_t OFF_BIAS   = 202482176;           // 1,024
  const size_t OFF_WIN    = 202483200;           // 800,000
  const size_t NEED       = 203283200;

  float code = 0.f;
  if (ws_size < NEED)                      code = 7.f;
  else if (n_in != 22)                     code = 9.f;
  else if (in_sizes[0] != BATCH)           code = 11.f;
  else if (in_sizes[10] != NNZ)            code = 13.f;
  else if (out_size != 3*BATCH*OUTW)       code = 19.f;
  if (code != 0.f){
    k_fill<<<(out_size + 255)/256, 256, 0, stream>>>(out, out_size, code);
    return;
  }

  const int* u_id  = (const int*)d_in[0];
  const int* age   = (const int*)d_in[1];
  const int* sex   = (const int*)d_in[2];
  const int* month = (const int*)d_in[3];
  const int* day   = (const int*)d_in[4];
  const int* dow   = (const int*)d_in[5];
  const int* pos   = (const int*)d_in[6];
  const int* neg   = (const int*)d_in[7];
  const int* lrows = (const int*)d_in[8];
  const int* lcols = (const int*)d_in[9];
  const float* lvals    = (const float*)d_in[10];
  const float* user_tab = (const float*)d_in[11];
  const float* item_tab = (const float*)d_in[12];
  const float* age_tab  = (const float*)d_in[13];
  const float* sex_tab  = (const float*)d_in[14];
  const float* month_tab= (const float*)d_in[15];
  const float* day_tab  = (const float*)d_in[16];
  const float* dow_tab  = (const float*)d_in[17];
  const float* W1 = (const float*)d_in[18];
  const float* b1 = (const float*)d_in[19];
  const float* W2 = (const float*)d_in[20];
  const float* b2 = (const float*)d_in[21];

  char* ws = (char*)d_ws;
  float* E0     = (float*)(ws + OFF_E0);
  float* E1     = (float*)(ws + OFF_E1);
  int* rowptr   = (int*)(ws + OFF_ROWPTR);
  int* cursor   = (int*)(ws + OFF_CURSOR);
  int2* edges   = (int2*)(ws + OFF_EDGES);
  int* bsum     = (int*)(ws + OFF_BSUM);
  unsigned short* Wt = (unsigned short*)(ws + OFF_WT);
  float* biasf  = (float*)(ws + OFF_BIAS);
  int* winner   = (int*)(ws + OFF_WIN);

  // ---- prologue: build E0 ----
  hipMemsetAsync(winner, 0xFF, N_USER*sizeof(int), stream);
  k_winner<<<(BATCH+255)/256, 256, 0, stream>>>(u_id, winner);
  k_copy4<<<(N_NODES*EMB/4+255)/256, 256, 0, stream>>>((const float4*)user_tab, (const float4*)item_tab, (float4*)E0);
  k_scatter_blend<<<(BATCH*EMB+255)/256, 256, 0, stream>>>(u_id, winner, age, sex, month, day, dow,
                                                   user_tab, age_tab, sex_tab, month_tab,
                                                   day_tab, dow_tab, E0);
  k_prep<<<(NL*EMB*160 + NL*EMB + 255)/256, 256, 0, stream>>>(W1, W2, b1, b2, Wt, biasf);

  // ---- CSR build ----
  hipMemsetAsync(rowptr, 0, (N_NODES+1)*sizeof(int), stream);
  k_hist<<<(NNZ+255)/256, 256, 0, stream>>>(lrows, rowptr);
  k_scan1<<<NSCAN_BLOCKS, 256, 0, stream>>>(rowptr, bsum);
  k_scan2<<<1, 512, 0, stream>>>(bsum);
  k_scan3<<<(N_NODES+255)/256, 256, 0, stream>>>(rowptr, bsum, cursor);
  k_scatter_edges<<<(NNZ+255)/256, 256, 0, stream>>>(lrows, lcols, lvals, cursor, edges);

  // layer-0 slice (raw E0)
  k_gather_wave<<<(3*BATCH+3)/4, 256, 0, stream>>>(E0, u_id, pos, neg, out, 0, 0);

  // ---- layers (ping-pong E0 <-> E1) ----
  float* Ein = E0; float* Eout = E1;
  for (int i = 0; i < NL; i++){
    k_fused2<<<(N_NODES+63)/64, 256, 0, stream>>>(Ein, Eout, rowptr, edges,
                                                  Wt + i*EMB*160, biasf + i*EMB);
    k_gather_wave<<<(3*BATCH+3)/4, 256, 0, stream>>>(Eout, u_id, pos, neg, out, i+1, 1);
    float* t = Ein; Ein = Eout; Eout = t;
  }
}

// Round 4
// 659.801 us; speedup vs baseline: 1.3536x; 1.0090x over previous
//
#include <hip/hip_runtime.h>
#include <hip/hip_bf16.h>

#define N_USER 200000
#define N_ITEM 100000
#define N_NODES 300000
#define EMB 80
#define FEAT 16
#define NL 3
#define NNZ 1000000
#define BATCH 4096
#define OUTW 320

typedef __bf16 bf16x8 __attribute__((ext_vector_type(8)));
typedef float f32x4 __attribute__((ext_vector_type(4)));

__device__ __forceinline__ unsigned short f2bf(float f){
  union { float f; unsigned int i; } x; x.f = f;
  unsigned int i = x.i;
  unsigned int r = i + 0x7fff + ((i >> 16) & 1u);
  return (unsigned short)(r >> 16);
}

// ---- diagnostic fill ----
__global__ void k_fill(float* out, int n, float v){
  int i = blockIdx.x * blockDim.x + threadIdx.x;
  if (i < n) out[i] = v;
}

// ---- winner: last write wins for duplicate u_id ----
__global__ void k_winner(const int* __restrict__ u_id, int* __restrict__ winner){
  int b = blockIdx.x * blockDim.x + threadIdx.x;
  if (b >= BATCH) return;
  atomicMax(&winner[u_id[b]], b);
}

// ---- E = concat(user_tab, item_tab), float4 ----
__global__ void k_copy4(const float4* __restrict__ user_tab, const float4* __restrict__ item_tab,
                        float4* __restrict__ E){
  int idx = blockIdx.x * blockDim.x + threadIdx.x;
  if (idx >= N_NODES*EMB/4) return;
  E[idx] = (idx < N_USER*EMB/4) ? user_tab[idx] : item_tab[idx - N_USER*EMB/4];
}

// ---- blended scatter: E[u_id[b]] = 0.5*(user_tab[u]+feat[b]) for winning b ----
__global__ void k_scatter_blend(const int* __restrict__ u_id, const int* __restrict__ winner,
                        const int* __restrict__ age, const int* __restrict__ sex,
                        const int* __restrict__ month, const int* __restrict__ day,
                        const int* __restrict__ dow,
                        const float* __restrict__ user_tab,
                        const float* __restrict__ age_tab, const float* __restrict__ sex_tab,
                        const float* __restrict__ month_tab, const float* __restrict__ day_tab,
                        const float* __restrict__ dow_tab,
                        float* __restrict__ E){
  int idx = blockIdx.x * blockDim.x + threadIdx.x;
  if (idx >= BATCH*EMB) return;
  int b = idx / EMB;
  int c = idx - b*EMB;
  int u = u_id[b];
  if (winner[u] != b) return;
  int t = c >> 4, cc = c & 15;
  int key; const float* tab;
  switch (t){
    case 0: key = age[b];   tab = age_tab;   break;
    case 1: key = sex[b];   tab = sex_tab;   break;
    case 2: key = month[b]; tab = month_tab; break;
    case 3: key = day[b];   tab = day_tab;   break;
    default: key = dow[b];  tab = dow_tab;   break;
  }
  float f = tab[key*FEAT + cc];
  E[(size_t)u*EMB + c] = 0.5f * user_tab[(size_t)u*EMB + c] + 0.5f * f;
}

// ---- prep: Wt[i][n][k] = stacked [W1;W2]^T (bf16, n-major), biasf = 2*b1+b2 ----
__global__ void k_prep(const float* __restrict__ W1, const float* __restrict__ W2,
                       const float* __restrict__ b1, const float* __restrict__ b2,
                       unsigned short* __restrict__ Wt, float* __restrict__ biasf){
  int idx = blockIdx.x * blockDim.x + threadIdx.x;
  if (idx < NL*EMB*160){
    int i = idx / (EMB*160);
    int rem = idx - i*(EMB*160);
    int n = rem / 160;
    int k = rem - n*160;
    float v = (k < EMB) ? W1[i*EMB*EMB + k*EMB + n] : W2[i*EMB*EMB + (k-EMB)*EMB + n];
    Wt[idx] = f2bf(v);
  } else if (idx < NL*EMB*160 + NL*EMB){
    int t = idx - NL*EMB*160;
    biasf[t] = 2.0f * b1[t] + b2[t];
  }
}

// ================= CSR build =================
__global__ void k_hist(const int* __restrict__ rows, int* __restrict__ cnt){
  int e = blockIdx.x * blockDim.x + threadIdx.x;
  if (e < NNZ) atomicAdd(&cnt[rows[e]], 1);
}

#define SCAN_BLK 1024
__global__ void k_scan1(int* __restrict__ cnt, int* __restrict__ bsum){
  __shared__ int s[256];
  int tid = threadIdx.x;
  int base = blockIdx.x * SCAN_BLK + tid*4;
  int v[4]; int sum = 0;
  #pragma unroll
  for (int j = 0; j < 4; j++){
    int i = base + j;
    v[j] = (i < N_NODES) ? cnt[i] : 0;
    sum += v[j];
  }
  s[tid] = sum; __syncthreads();
  int own = sum;
  for (int d = 1; d < 256; d <<= 1){
    int t = (tid >= d) ? s[tid-d] : 0;
    __syncthreads();
    s[tid] += t;
    __syncthreads();
  }
  int excl = s[tid] - own;
  if (tid == 0) bsum[blockIdx.x] = s[255];
  int run = excl;
  #pragma unroll
  for (int j = 0; j < 4; j++){
    int i = base + j;
    if (i < N_NODES) cnt[i] = run;
    run += v[j];
  }
}

#define NSCAN_BLOCKS ((N_NODES + SCAN_BLK - 1)/SCAN_BLK)   // 293
__global__ void k_scan2(int* __restrict__ bsum){
  __shared__ int s[512];
  int tid = threadIdx.x;
  int v = (tid < NSCAN_BLOCKS) ? bsum[tid] : 0;
  s[tid] = v; __syncthreads();
  for (int d = 1; d < 512; d <<= 1){
    int t = (tid >= d) ? s[tid-d] : 0;
    __syncthreads();
    s[tid] += t;
    __syncthreads();
  }
  if (tid < NSCAN_BLOCKS) bsum[tid] = s[tid] - v;
}

__global__ void k_scan3(int* __restrict__ rowptr, const int* __restrict__ bsum,
                        int* __restrict__ cursor){
  int i = blockIdx.x * blockDim.x + threadIdx.x;
  if (i >= N_NODES) return;
  int v = rowptr[i] + bsum[i >> 10];
  rowptr[i] = v;
  cursor[i] = v;
  if (i == 0) rowptr[N_NODES] = NNZ;
}

// edges[pos] = {col, bitcast(val)} — one 8B store instead of two 4B scatters
__global__ void k_scatter_edges(const int* __restrict__ rows, const int* __restrict__ cols,
                                const float* __restrict__ vals,
                                int* __restrict__ cursor,
                                int2* __restrict__ edges){
  int e = blockIdx.x * blockDim.x + threadIdx.x;
  if (e >= NNZ) return;
  int r = rows[e];
  int pos = atomicAdd(&cursor[r], 1);
  int2 ed; ed.x = cols[e]; ed.y = __float_as_int(vals[e]);
  edges[pos] = ed;
}

// ==== fused layer v5: LDS-staged rowptr+edges; single barrier; wave-local phase2 ====
#define LE_PAD 84      // floats; 336 B row stride
#define EDGE_CAP 512   // block edge slab; mean 213, sd ~15 -> 20 sigma headroom
__launch_bounds__(256)
__global__ void k_fused2(const float* __restrict__ Ein, float* __restrict__ Eout,
                         const int* __restrict__ rowptr, const int2* __restrict__ edges,
                         const unsigned short* __restrict__ Wt, const float* __restrict__ biasf){
  __shared__ float le[64 * LE_PAD];   // 21504 B
  __shared__ int2  sedge[EDGE_CAP];   //  4096 B
  __shared__ int   srp[65];           //   260 B  -> 25860 B total
  int tid = threadIdx.x;
  long row0 = (long)blockIdx.x * 64;

  int lane = tid & 63;
  int wave = tid >> 6;
  int m = lane & 15;
  int quad = lane >> 4;

  // stage rowptr slice (coalesced 65-lane load -> LDS)
  if (tid < 65){
    long rr = row0 + tid;
    if (rr > N_NODES) rr = N_NODES;
    srp[tid] = rowptr[rr];
  }

  // uniform block edge range via s_load (row0 uniform)
  long rend = row0 + 64; if (rend > N_NODES) rend = N_NODES;
  int s0 = rowptr[row0];
  int n  = rowptr[rend] - s0;

  // stage edge slab (coalesced burst); fallback path if absurdly dense block
  bool fit = (n <= EDGE_CAP);
  if (fit){
    for (int i = tid; i < n; i += 256) sedge[i] = edges[s0 + i];
  }
  __syncthreads();   // the ONLY block barrier

  // phase 1: owner-computes. thread -> (row tid>>2, 20-float chunk tid&3).
  // edges come from LDS (50cyc) -> single global-latency round (the gathers).
  {
    int lr = tid >> 2;
    int qg = tid & 3;
    int ls  = srp[lr]   - s0;
    int le_ = srp[lr+1] - s0;
    const float* eb = Ein + qg*20;
    f32x4 a[5];
    #pragma unroll
    for (int j = 0; j < 5; j++) a[j] = (f32x4){0.f,0.f,0.f,0.f};
    int ilast = le_ - 1;
    if (fit){
      for (int i = ls; i < le_; i += 4){
        int rem = le_ - i;
        int2 ed0 = sedge[i];
        int2 ed1 = sedge[min(i+1, ilast)];
        int2 ed2 = sedge[min(i+2, ilast)];
        int2 ed3 = sedge[min(i+3, ilast)];
        float v0 = __int_as_float(ed0.y);
        float v1 = (rem > 1) ? __int_as_float(ed1.y) : 0.f;
        float v2 = (rem > 2) ? __int_as_float(ed2.y) : 0.f;
        float v3 = (rem > 3) ? __int_as_float(ed3.y) : 0.f;
        const float* g0 = eb + (size_t)ed0.x*EMB;
        const float* g1 = eb + (size_t)ed1.x*EMB;
        const float* g2 = eb + (size_t)ed2.x*EMB;
        const float* g3 = eb + (size_t)ed3.x*EMB;
        #pragma unroll
        for (int j = 0; j < 5; j++){
          float4 x0 = *(const float4*)(g0 + j*4);
          float4 x1 = *(const float4*)(g1 + j*4);
          float4 x2 = *(const float4*)(g2 + j*4);
          float4 x3 = *(const float4*)(g3 + j*4);
          a[j].x += v0*x0.x + v1*x1.x + v2*x2.x + v3*x3.x;
          a[j].y += v0*x0.y + v1*x1.y + v2*x2.y + v3*x3.y;
          a[j].z += v0*x0.z + v1*x1.z + v2*x2.z + v3*x3.z;
          a[j].w += v0*x0.w + v1*x1.w + v2*x2.w + v3*x3.w;
        }
      }
    } else {
      for (int i = ls; i < le_; i += 4){
        int rem = le_ - i;
        int2 ed0 = edges[s0 + i];
        int2 ed1 = edges[s0 + min(i+1, ilast)];
        int2 ed2 = edges[s0 + min(i+2, ilast)];
        int2 ed3 = edges[s0 + min(i+3, ilast)];
        float v0 = __int_as_float(ed0.y);
        float v1 = (rem > 1) ? __int_as_float(ed1.y) : 0.f;
        float v2 = (rem > 2) ? __int_as_float(ed2.y) : 0.f;
        float v3 = (rem > 3) ? __int_as_float(ed3.y) : 0.f;
        const float* g0 = eb + (size_t)ed0.x*EMB;
        const float* g1 = eb + (size_t)ed1.x*EMB;
        const float* g2 = eb + (size_t)ed2.x*EMB;
        const float* g3 = eb + (size_t)ed3.x*EMB;
        #pragma unroll
        for (int j = 0; j < 5; j++){
          float4 x0 = *(const float4*)(g0 + j*4);
          float4 x1 = *(const float4*)(g1 + j*4);
          float4 x2 = *(const float4*)(g2 + j*4);
          float4 x3 = *(const float4*)(g3 + j*4);
          a[j].x += v0*x0.x + v1*x1.x + v2*x2.x + v3*x3.x;
          a[j].y += v0*x0.y + v1*x1.y + v2*x2.y + v3*x3.y;
          a[j].z += v0*x0.z + v1*x1.z + v2*x2.z + v3*x3.z;
          a[j].w += v0*x0.w + v1*x1.w + v2*x2.w + v3*x3.w;
        }
      }
    }
    float* lp = le + lr*LE_PAD + qg*20;
    #pragma unroll
    for (int j = 0; j < 5; j++) *(f32x4*)(lp + j*4) = a[j];
  }

  // B fragments (Wt n-major) — issued here so they overlap the lgkm drain
  bf16x8 bfrag[5][5];
  #pragma unroll
  for (int nt = 0; nt < 5; nt++)
    #pragma unroll
    for (int kt = 0; kt < 5; kt++)
      bfrag[nt][kt] = *(const bf16x8*)(Wt + (nt*16 + m)*160 + kt*32 + quad*8);

  // wave-local sync: wave w wrote LDS rows 16w..16w+15 and reads exactly those.
  // No cross-wave LDS dependency remains -> s_waitcnt instead of s_barrier.
  asm volatile("s_waitcnt lgkmcnt(0)" ::: "memory");
  __builtin_amdgcn_sched_barrier(0);

  // phase 2: K=160 GEMM, A-fragments in registers
  int arow = wave*16 + m;                 // LDS row this lane reads (own wave's rows)
  long rA = row0 + arow;
  const float* erow = Ein + (size_t)(rA < N_NODES ? rA : 0) * EMB;
  const float* lrow = le + arow*LE_PAD;

  f32x4 acc[5];
  #pragma unroll
  for (int nt = 0; nt < 5; nt++) acc[nt] = (f32x4){0.f,0.f,0.f,0.f};

  #pragma unroll
  for (int kt = 0; kt < 5; kt++){
    int k8 = kt*32 + quad*8;              // 8 consecutive k's; never crosses 80 (80%8==0)
    bool addh = (k8 < EMB);
    int c8 = addh ? k8 : k8 - EMB;
    float4 e0 = *(const float4*)(erow + c8);
    float4 e1 = *(const float4*)(erow + c8 + 4);
    float4 l0 = *(const float4*)(lrow + c8);
    float4 l1 = *(const float4*)(lrow + c8 + 4);
    float x0,x1,x2,x3,x4,x5,x6,x7;
    if (addh){
      x0=e0.x+l0.x; x1=e0.y+l0.y; x2=e0.z+l0.z; x3=e0.w+l0.w;
      x4=e1.x+l1.x; x5=e1.y+l1.y; x6=e1.z+l1.z; x7=e1.w+l1.w;
    } else {
      x0=e0.x*l0.x; x1=e0.y*l0.y; x2=e0.z*l0.z; x3=e0.w*l0.w;
      x4=e1.x*l1.x; x5=e1.y*l1.y; x6=e1.z*l1.z; x7=e1.w*l1.w;
    }
    bf16x8 af;
    af[0]=(__bf16)x0; af[1]=(__bf16)x1; af[2]=(__bf16)x2; af[3]=(__bf16)x3;
    af[4]=(__bf16)x4; af[5]=(__bf16)x5; af[6]=(__bf16)x6; af[7]=(__bf16)x7;
    #pragma unroll
    for (int nt = 0; nt < 5; nt++)
      acc[nt] = __builtin_amdgcn_mfma_f32_16x16x32_bf16(af, bfrag[nt][kt], acc[nt], 0, 0, 0);
  }

  // epilogue: C/D layout col=lane&15, row=quad*4+reg
  long rbase = row0 + wave*16 + quad*4;
  #pragma unroll
  for (int nt = 0; nt < 5; nt++){
    int col = nt*16 + m;
    float b = biasf[col];
    #pragma unroll
    for (int i = 0; i < 4; i++){
      long r = rbase + i;
      if (r < N_NODES){
        float v = acc[nt][i] + b;
        Eout[r*EMB + col] = (v > 0.f) ? v : 0.2f * v;
      }
    }
  }
}

// ---- fused gather + row L2 norm (wave per gathered row), fp32 out ----
__global__ void k_gather_wave(const float* __restrict__ E, const int* __restrict__ u_id,
                              const int* __restrict__ pos, const int* __restrict__ neg,
                              float* __restrict__ out, int layer, int do_norm){
  int gw = blockIdx.x * (blockDim.x >> 6) + (threadIdx.x >> 6);
  if (gw >= 3*BATCH) return;
  int lane = threadIdx.x & 63;
  int chunk = gw / BATCH;
  int b = gw - chunk*BATCH;
  int node = (chunk == 0) ? u_id[b] : ((chunk == 1) ? N_USER + pos[b] : N_USER + neg[b]);
  const float* er = E + (size_t)node*EMB;
  float v0 = er[lane];
  float v1 = (lane < EMB-64) ? er[64 + lane] : 0.f;
  float scale = 1.f;
  if (do_norm){
    float ss = v0*v0 + v1*v1;
    #pragma unroll
    for (int s = 32; s > 0; s >>= 1) ss += __shfl_xor(ss, s, 64);
    float nrm = fmaxf(sqrtf(ss), 1e-12f);
    scale = 1.f / nrm;
  }
  float* po = out + (size_t)chunk*BATCH*OUTW + (size_t)b*OUTW + layer*EMB;
  po[lane] = v0 * scale;
  if (lane < EMB-64) po[64 + lane] = v1 * scale;
}

extern "C" void kernel_launch(void* const* d_in, const int* in_sizes, int n_in,
                              void* d_out, int out_size, void* d_ws, size_t ws_size,
                              hipStream_t stream) {
  float* out = (float*)d_out;

  const size_t OFF_E0     = 0;                   // 96,000,000
  const size_t OFF_E1     = 96000000;            // 96,000,000
  const size_t OFF_ROWPTR = 192000000;           // 1,200,640
  const size_t OFF_CURSOR = 193200640;           // 1,200,640
  const size_t OFF_EDGES  = 194401280;           // 8,000,000 (int2 per edge)
  const size_t OFF_BSUM   = 202401280;           // 4,096
  const size_t OFF_WT     = 202405376;           // 76,800
  const size_t OFF_BIAS   = 202482176;           // 1,024
  const size_t OFF_WIN    = 202483200;           // 800,000
  const size_t NEED       = 203283200;

  float code = 0.f;
  if (ws_size < NEED)                      code = 7.f;
  else if (n_in != 22)                     code = 9.f;
  else if (in_sizes[0] != BATCH)           code = 11.f;
  else if (in_sizes[10] != NNZ)            code = 13.f;
  else if (out_size != 3*BATCH*OUTW)       code = 19.f;
  if (code != 0.f){
    k_fill<<<(out_size + 255)/256, 256, 0, stream>>>(out, out_size, code);
    return;
  }

  const int* u_id  = (const int*)d_in[0];
  const int* age   = (const int*)d_in[1];
  const int* sex   = (const int*)d_in[2];
  const int* month = (const int*)d_in[3];
  const int* day   = (const int*)d_in[4];
  const int* dow   = (const int*)d_in[5];
  const int* pos   = (const int*)d_in[6];
  const int* neg   = (const int*)d_in[7];
  const int* lrows = (const int*)d_in[8];
  const int* lcols = (const int*)d_in[9];
  const float* lvals    = (const float*)d_in[10];
  const float* user_tab = (const float*)d_in[11];
  const float* item_tab = (const float*)d_in[12];
  const float* age_tab  = (const float*)d_in[13];
  const float* sex_tab  = (const float*)d_in[14];
  const float* month_tab= (const float*)d_in[15];
  const float* day_tab  = (const float*)d_in[16];
  const float* dow_tab  = (const float*)d_in[17];
  const float* W1 = (const float*)d_in[18];
  const float* b1 = (const float*)d_in[19];
  const float* W2 = (const float*)d_in[20];
  const float* b2 = (const float*)d_in[21];

  char* ws = (char*)d_ws;
  float* E0     = (float*)(ws + OFF_E0);
  float* E1     = (float*)(ws + OFF_E1);
  int* rowptr   = (int*)(ws + OFF_ROWPTR);
  int* cursor   = (int*)(ws + OFF_CURSOR);
  int2* edges   = (int2*)(ws + OFF_EDGES);
  int* bsum     = (int*)(ws + OFF_BSUM);
  unsigned short* Wt = (unsigned short*)(ws + OFF_WT);
  float* biasf  = (float*)(ws + OFF_BIAS);
  int* winner   = (int*)(ws + OFF_WIN);

  // ---- prologue: build E0 ----
  hipMemsetAsync(winner, 0xFF, N_USER*sizeof(int), stream);
  k_winner<<<(BATCH+255)/256, 256, 0, stream>>>(u_id, winner);
  k_copy4<<<(N_NODES*EMB/4+255)/256, 256, 0, stream>>>((const float4*)user_tab, (const float4*)item_tab, (float4*)E0);
  k_scatter_blend<<<(BATCH*EMB+255)/256, 256, 0, stream>>>(u_id, winner, age, sex, month, day, dow,
                                                   user_tab, age_tab, sex_tab, month_tab,
                                                   day_tab, dow_tab, E0);
  k_prep<<<(NL*EMB*160 + NL*EMB + 255)/256, 256, 0, stream>>>(W1, W2, b1, b2, Wt, biasf);

  // ---- CSR build ----
  hipMemsetAsync(rowptr, 0, (N_NODES+1)*sizeof(int), stream);
  k_hist<<<(NNZ+255)/256, 256, 0, stream>>>(lrows, rowptr);
  k_scan1<<<NSCAN_BLOCKS, 256, 0, stream>>>(rowptr, bsum);
  k_scan2<<<1, 512, 0, stream>>>(bsum);
  k_scan3<<<(N_NODES+255)/256, 256, 0, stream>>>(rowptr, bsum, cursor);
  k_scatter_edges<<<(NNZ+255)/256, 256, 0, stream>>>(lrows, lcols, lvals, cursor, edges);

  // layer-0 slice (raw E0)
  k_gather_wave<<<(3*BATCH+3)/4, 256, 0, stream>>>(E0, u_id, pos, neg, out, 0, 0);

  // ---- layers (ping-pong E0 <-> E1) ----
  float* Ein = E0; float* Eout = E1;
  for (int i = 0; i < NL; i++){
    k_fused2<<<(N_NODES+63)/64, 256, 0, stream>>>(Ein, Eout, rowptr, edges,
                                                  Wt + i*EMB*160, biasf + i*EMB);
    k_gather_wave<<<(3*BATCH+3)/4, 256, 0, stream>>>(Eout, u_id, pos, neg, out, i+1, 1);
    float* t = Ein; Ein = Eout; Eout = t;
  }
}

// Round 5
// 653.476 us; speedup vs baseline: 1.3667x; 1.0097x over previous
//
#include <hip/hip_runtime.h>
#include <hip/hip_bf16.h>

#define N_USER 200000
#define N_ITEM 100000
#define N_NODES 300000
#define EMB 80
#define FEAT 16
#define NL 3
#define NNZ 1000000
#define BATCH 4096
#define OUTW 320

typedef __bf16 bf16x8 __attribute__((ext_vector_type(8)));
typedef float f32x4 __attribute__((ext_vector_type(4)));

__device__ __forceinline__ unsigned short f2bf(float f){
  union { float f; unsigned int i; } x; x.f = f;
  unsigned int i = x.i;
  unsigned int r = i + 0x7fff + ((i >> 16) & 1u);
  return (unsigned short)(r >> 16);
}

// ---- diagnostic fill ----
__global__ void k_fill(float* out, int n, float v){
  int i = blockIdx.x * blockDim.x + threadIdx.x;
  if (i < n) out[i] = v;
}

// ---- winner: last write wins for duplicate u_id ----
__global__ void k_winner(const int* __restrict__ u_id, int* __restrict__ winner){
  int b = blockIdx.x * blockDim.x + threadIdx.x;
  if (b >= BATCH) return;
  atomicMax(&winner[u_id[b]], b);
}

// ---- E = concat(user_tab, item_tab), float4 ----
__global__ void k_copy4(const float4* __restrict__ user_tab, const float4* __restrict__ item_tab,
                        float4* __restrict__ E){
  int idx = blockIdx.x * blockDim.x + threadIdx.x;
  if (idx >= N_NODES*EMB/4) return;
  E[idx] = (idx < N_USER*EMB/4) ? user_tab[idx] : item_tab[idx - N_USER*EMB/4];
}

// ---- blended scatter: E[u_id[b]] = 0.5*(user_tab[u]+feat[b]) for winning b ----
__global__ void k_scatter_blend(const int* __restrict__ u_id, const int* __restrict__ winner,
                        const int* __restrict__ age, const int* __restrict__ sex,
                        const int* __restrict__ month, const int* __restrict__ day,
                        const int* __restrict__ dow,
                        const float* __restrict__ user_tab,
                        const float* __restrict__ age_tab, const float* __restrict__ sex_tab,
                        const float* __restrict__ month_tab, const float* __restrict__ day_tab,
                        const float* __restrict__ dow_tab,
                        float* __restrict__ E){
  int idx = blockIdx.x * blockDim.x + threadIdx.x;
  if (idx >= BATCH*EMB) return;
  int b = idx / EMB;
  int c = idx - b*EMB;
  int u = u_id[b];
  if (winner[u] != b) return;
  int t = c >> 4, cc = c & 15;
  int key; const float* tab;
  switch (t){
    case 0: key = age[b];   tab = age_tab;   break;
    case 1: key = sex[b];   tab = sex_tab;   break;
    case 2: key = month[b]; tab = month_tab; break;
    case 3: key = day[b];   tab = day_tab;   break;
    default: key = dow[b];  tab = dow_tab;   break;
  }
  float f = tab[key*FEAT + cc];
  E[(size_t)u*EMB + c] = 0.5f * user_tab[(size_t)u*EMB + c] + 0.5f * f;
}

// ---- prep: Wt[i][n][k] = stacked [W1;W2]^T (bf16, n-major), biasf = 2*b1+b2 ----
__global__ void k_prep(const float* __restrict__ W1, const float* __restrict__ W2,
                       const float* __restrict__ b1, const float* __restrict__ b2,
                       unsigned short* __restrict__ Wt, float* __restrict__ biasf){
  int idx = blockIdx.x * blockDim.x + threadIdx.x;
  if (idx < NL*EMB*160){
    int i = idx / (EMB*160);
    int rem = idx - i*(EMB*160);
    int n = rem / 160;
    int k = rem - n*160;
    float v = (k < EMB) ? W1[i*EMB*EMB + k*EMB + n] : W2[i*EMB*EMB + (k-EMB)*EMB + n];
    Wt[idx] = f2bf(v);
  } else if (idx < NL*EMB*160 + NL*EMB){
    int t = idx - NL*EMB*160;
    biasf[t] = 2.0f * b1[t] + b2[t];
  }
}

// ================= CSR build =================
__global__ void k_hist(const int* __restrict__ rows, int* __restrict__ cnt){
  int e = blockIdx.x * blockDim.x + threadIdx.x;
  if (e < NNZ) atomicAdd(&cnt[rows[e]], 1);
}

#define SCAN_BLK 1024
__global__ void k_scan1(int* __restrict__ cnt, int* __restrict__ bsum){
  __shared__ int s[256];
  int tid = threadIdx.x;
  int base = blockIdx.x * SCAN_BLK + tid*4;
  int v[4]; int sum = 0;
  #pragma unroll
  for (int j = 0; j < 4; j++){
    int i = base + j;
    v[j] = (i < N_NODES) ? cnt[i] : 0;
    sum += v[j];
  }
  s[tid] = sum; __syncthreads();
  int own = sum;
  for (int d = 1; d < 256; d <<= 1){
    int t = (tid >= d) ? s[tid-d] : 0;
    __syncthreads();
    s[tid] += t;
    __syncthreads();
  }
  int excl = s[tid] - own;
  if (tid == 0) bsum[blockIdx.x] = s[255];
  int run = excl;
  #pragma unroll
  for (int j = 0; j < 4; j++){
    int i = base + j;
    if (i < N_NODES) cnt[i] = run;
    run += v[j];
  }
}

#define NSCAN_BLOCKS ((N_NODES + SCAN_BLK - 1)/SCAN_BLK)   // 293
__global__ void k_scan2(int* __restrict__ bsum){
  __shared__ int s[512];
  int tid = threadIdx.x;
  int v = (tid < NSCAN_BLOCKS) ? bsum[tid] : 0;
  s[tid] = v; __syncthreads();
  for (int d = 1; d < 512; d <<= 1){
    int t = (tid >= d) ? s[tid-d] : 0;
    __syncthreads();
    s[tid] += t;
    __syncthreads();
  }
  if (tid < NSCAN_BLOCKS) bsum[tid] = s[tid] - v;
}

__global__ void k_scan3(int* __restrict__ rowptr, const int* __restrict__ bsum,
                        int* __restrict__ cursor){
  int i = blockIdx.x * blockDim.x + threadIdx.x;
  if (i >= N_NODES) return;
  int v = rowptr[i] + bsum[i >> 10];
  rowptr[i] = v;
  cursor[i] = v;
  if (i == 0) rowptr[N_NODES] = NNZ;
}

// edges[pos] = {col, bitcast(val)} — one 8B store instead of two 4B scatters
__global__ void k_scatter_edges(const int* __restrict__ rows, const int* __restrict__ cols,
                                const float* __restrict__ vals,
                                int* __restrict__ cursor,
                                int2* __restrict__ edges){
  int e = blockIdx.x * blockDim.x + threadIdx.x;
  if (e >= NNZ) return;
  int r = rows[e];
  int pos = atomicAdd(&cursor[r], 1);
  int2 ed; ed.x = cols[e]; ed.y = __float_as_int(vals[e]);
  edges[pos] = ed;
}

// ==== fused layer v6: zero barriers (wave-autonomous) + stride-4 interleaved gather ====
// Wave w's phase-1 lanes (lr=tid>>2) cover rows 16w..16w+15 == exactly the rows
// wave w consumes in phase 2 -> no cross-wave LDS dependency -> no __syncthreads.
// Thread qg owns float4s {qg,4+qg,...,16+qg}: per j-instruction the 4 qg-lanes of a
// row read CONTIGUOUS 64B -> ~20 distinct lines/instr instead of ~42 (5x re-touch).
#define LE_PAD 84   // floats; 336 B row stride
__launch_bounds__(256)
__global__ void k_fused2(const float* __restrict__ Ein, float* __restrict__ Eout,
                         const int* __restrict__ rowptr, const int2* __restrict__ edges,
                         const unsigned short* __restrict__ Wt, const float* __restrict__ biasf){
  __shared__ float le[64 * LE_PAD];   // 21504 B -> 7 blocks/CU by LDS
  int tid = threadIdx.x;
  long row0 = (long)blockIdx.x * 64;

  int lane = tid & 63;
  int wave = tid >> 6;
  int m = lane & 15;
  int quad = lane >> 4;

  // phase 1: CSR SpMM rows -> LDS. Thread (row tid>>2, interleave-slot tid&3).
  {
    int lr = tid >> 2;
    int qg = tid & 3;
    long r = row0 + lr;
    int s = 0, e = 0;
    if (r < N_NODES){ s = rowptr[r]; e = rowptr[r+1]; }
    const float* eb = Ein + qg*4;      // first owned float4 of each gathered row
    f32x4 a[5];                        // a[j] = float4 #(4j+qg) of L_E row
    #pragma unroll
    for (int j = 0; j < 5; j++) a[j] = (f32x4){0.f,0.f,0.f,0.f};
    int ilast = e - 1;
    for (int i = s; i < e; i += 4){
      int rem = e - i;
      int2 ed0 = edges[i];
      int2 ed1 = edges[min(i+1, ilast)];
      int2 ed2 = edges[min(i+2, ilast)];
      int2 ed3 = edges[min(i+3, ilast)];
      float v0 = __int_as_float(ed0.y);
      float v1 = (rem > 1) ? __int_as_float(ed1.y) : 0.f;
      float v2 = (rem > 2) ? __int_as_float(ed2.y) : 0.f;
      float v3 = (rem > 3) ? __int_as_float(ed3.y) : 0.f;
      const float* g0 = eb + (size_t)ed0.x*EMB;
      const float* g1 = eb + (size_t)ed1.x*EMB;
      const float* g2 = eb + (size_t)ed2.x*EMB;
      const float* g3 = eb + (size_t)ed3.x*EMB;
      #pragma unroll
      for (int j = 0; j < 5; j++){
        float4 x0 = *(const float4*)(g0 + j*16);
        float4 x1 = *(const float4*)(g1 + j*16);
        float4 x2 = *(const float4*)(g2 + j*16);
        float4 x3 = *(const float4*)(g3 + j*16);
        a[j].x += v0*x0.x + v1*x1.x + v2*x2.x + v3*x3.x;
        a[j].y += v0*x0.y + v1*x1.y + v2*x2.y + v3*x3.y;
        a[j].z += v0*x0.z + v1*x1.z + v2*x2.z + v3*x3.z;
        a[j].w += v0*x0.w + v1*x1.w + v2*x2.w + v3*x3.w;
      }
    }
    float* lp = le + lr*LE_PAD + qg*4;
    #pragma unroll
    for (int j = 0; j < 5; j++) *(f32x4*)(lp + j*16) = a[j];
  }

  // B fragments (Wt n-major) — after phase 1; overlap the lgkm drain
  bf16x8 bfrag[5][5];
  #pragma unroll
  for (int nt = 0; nt < 5; nt++)
    #pragma unroll
    for (int kt = 0; kt < 5; kt++)
      bfrag[nt][kt] = *(const bf16x8*)(Wt + (nt*16 + m)*160 + kt*32 + quad*8);

  // wave-local phase boundary: drain own LDS writes; no block barrier anywhere.
  asm volatile("s_waitcnt lgkmcnt(0)" ::: "memory");
  __builtin_amdgcn_sched_barrier(0);

  // phase 2: K=160 GEMM, A-fragments in registers
  int arow = wave*16 + m;                 // own wave's LDS rows only
  long rA = row0 + arow;
  const float* erow = Ein + (size_t)(rA < N_NODES ? rA : 0) * EMB;
  const float* lrow = le + arow*LE_PAD;

  f32x4 acc[5];
  #pragma unroll
  for (int nt = 0; nt < 5; nt++) acc[nt] = (f32x4){0.f,0.f,0.f,0.f};

  #pragma unroll
  for (int kt = 0; kt < 5; kt++){
    int k8 = kt*32 + quad*8;              // 8 consecutive k's; never crosses 80 (80%8==0)
    bool addh = (k8 < EMB);
    int c8 = addh ? k8 : k8 - EMB;
    float4 e0 = *(const float4*)(erow + c8);
    float4 e1 = *(const float4*)(erow + c8 + 4);
    float4 l0 = *(const float4*)(lrow + c8);
    float4 l1 = *(const float4*)(lrow + c8 + 4);
    float x0,x1,x2,x3,x4,x5,x6,x7;
    if (addh){
      x0=e0.x+l0.x; x1=e0.y+l0.y; x2=e0.z+l0.z; x3=e0.w+l0.w;
      x4=e1.x+l1.x; x5=e1.y+l1.y; x6=e1.z+l1.z; x7=e1.w+l1.w;
    } else {
      x0=e0.x*l0.x; x1=e0.y*l0.y; x2=e0.z*l0.z; x3=e0.w*l0.w;
      x4=e1.x*l1.x; x5=e1.y*l1.y; x6=e1.z*l1.z; x7=e1.w*l1.w;
    }
    bf16x8 af;
    af[0]=(__bf16)x0; af[1]=(__bf16)x1; af[2]=(__bf16)x2; af[3]=(__bf16)x3;
    af[4]=(__bf16)x4; af[5]=(__bf16)x5; af[6]=(__bf16)x6; af[7]=(__bf16)x7;
    #pragma unroll
    for (int nt = 0; nt < 5; nt++)
      acc[nt] = __builtin_amdgcn_mfma_f32_16x16x32_bf16(af, bfrag[nt][kt], acc[nt], 0, 0, 0);
  }

  // epilogue: C/D layout col=lane&15, row=quad*4+reg
  long rbase = row0 + wave*16 + quad*4;
  #pragma unroll
  for (int nt = 0; nt < 5; nt++){
    int col = nt*16 + m;
    float b = biasf[col];
    #pragma unroll
    for (int i = 0; i < 4; i++){
      long r = rbase + i;
      if (r < N_NODES){
        float v = acc[nt][i] + b;
        Eout[r*EMB + col] = (v > 0.f) ? v : 0.2f * v;
      }
    }
  }
}

// ---- fused gather + row L2 norm (wave per gathered row), fp32 out ----
__global__ void k_gather_wave(const float* __restrict__ E, const int* __restrict__ u_id,
                              const int* __restrict__ pos, const int* __restrict__ neg,
                              float* __restrict__ out, int layer, int do_norm){
  int gw = blockIdx.x * (blockDim.x >> 6) + (threadIdx.x >> 6);
  if (gw >= 3*BATCH) return;
  int lane = threadIdx.x & 63;
  int chunk = gw / BATCH;
  int b = gw - chunk*BATCH;
  int node = (chunk == 0) ? u_id[b] : ((chunk == 1) ? N_USER + pos[b] : N_USER + neg[b]);
  const float* er = E + (size_t)node*EMB;
  float v0 = er[lane];
  float v1 = (lane < EMB-64) ? er[64 + lane] : 0.f;
  float scale = 1.f;
  if (do_norm){
    float ss = v0*v0 + v1*v1;
    #pragma unroll
    for (int s = 32; s > 0; s >>= 1) ss += __shfl_xor(ss, s, 64);
    float nrm = fmaxf(sqrtf(ss), 1e-12f);
    scale = 1.f / nrm;
  }
  float* po = out + (size_t)chunk*BATCH*OUTW + (size_t)b*OUTW + layer*EMB;
  po[lane] = v0 * scale;
  if (lane < EMB-64) po[64 + lane] = v1 * scale;
}

extern "C" void kernel_launch(void* const* d_in, const int* in_sizes, int n_in,
                              void* d_out, int out_size, void* d_ws, size_t ws_size,
                              hipStream_t stream) {
  float* out = (float*)d_out;

  const size_t OFF_E0     = 0;                   // 96,000,000
  const size_t OFF_E1     = 96000000;            // 96,000,000
  const size_t OFF_ROWPTR = 192000000;           // 1,200,640
  const size_t OFF_CURSOR = 193200640;           // 1,200,640
  const size_t OFF_EDGES  = 194401280;           // 8,000,000 (int2 per edge)
  const size_t OFF_BSUM   = 202401280;           // 4,096
  const size_t OFF_WT     = 202405376;           // 76,800
  const size_t OFF_BIAS   = 202482176;           // 1,024
  const size_t OFF_WIN    = 202483200;           // 800,000
  const size_t NEED       = 203283200;

  float code = 0.f;
  if (ws_size < NEED)                      code = 7.f;
  else if (n_in != 22)                     code = 9.f;
  else if (in_sizes[0] != BATCH)           code = 11.f;
  else if (in_sizes[10] != NNZ)            code = 13.f;
  else if (out_size != 3*BATCH*OUTW)       code = 19.f;
  if (code != 0.f){
    k_fill<<<(out_size + 255)/256, 256, 0, stream>>>(out, out_size, code);
    return;
  }

  const int* u_id  = (const int*)d_in[0];
  const int* age   = (const int*)d_in[1];
  const int* sex   = (const int*)d_in[2];
  const int* month = (const int*)d_in[3];
  const int* day   = (const int*)d_in[4];
  const int* dow   = (const int*)d_in[5];
  const int* pos   = (const int*)d_in[6];
  const int* neg   = (const int*)d_in[7];
  const int* lrows = (const int*)d_in[8];
  const int* lcols = (const int*)d_in[9];
  const float* lvals    = (const float*)d_in[10];
  const float* user_tab = (const float*)d_in[11];
  const float* item_tab = (const float*)d_in[12];
  const float* age_tab  = (const float*)d_in[13];
  const float* sex_tab  = (const float*)d_in[14];
  const float* month_tab= (const float*)d_in[15];
  const float* day_tab  = (const float*)d_in[16];
  const float* dow_tab  = (const float*)d_in[17];
  const float* W1 = (const float*)d_in[18];
  const float* b1 = (const float*)d_in[19];
  const float* W2 = (const float*)d_in[20];
  const float* b2 = (const float*)d_in[21];

  char* ws = (char*)d_ws;
  float* E0     = (float*)(ws + OFF_E0);
  float* E1     = (float*)(ws + OFF_E1);
  int* rowptr   = (int*)(ws + OFF_ROWPTR);
  int* cursor   = (int*)(ws + OFF_CURSOR);
  int2* edges   = (int2*)(ws + OFF_EDGES);
  int* bsum     = (int*)(ws + OFF_BSUM);
  unsigned short* Wt = (unsigned short*)(ws + OFF_WT);
  float* biasf  = (float*)(ws + OFF_BIAS);
  int* winner   = (int*)(ws + OFF_WIN);

  // ---- prologue: build E0 ----
  hipMemsetAsync(winner, 0xFF, N_USER*sizeof(int), stream);
  k_winner<<<(BATCH+255)/256, 256, 0, stream>>>(u_id, winner);
  k_copy4<<<(N_NODES*EMB/4+255)/256, 256, 0, stream>>>((const float4*)user_tab, (const float4*)item_tab, (float4*)E0);
  k_scatter_blend<<<(BATCH*EMB+255)/256, 256, 0, stream>>>(u_id, winner, age, sex, month, day, dow,
                                                   user_tab, age_tab, sex_tab, month_tab,
                                                   day_tab, dow_tab, E0);
  k_prep<<<(NL*EMB*160 + NL*EMB + 255)/256, 256, 0, stream>>>(W1, W2, b1, b2, Wt, biasf);

  // ---- CSR build ----
  hipMemsetAsync(rowptr, 0, (N_NODES+1)*sizeof(int), stream);
  k_hist<<<(NNZ+255)/256, 256, 0, stream>>>(lrows, rowptr);
  k_scan1<<<NSCAN_BLOCKS, 256, 0, stream>>>(rowptr, bsum);
  k_scan2<<<1, 512, 0, stream>>>(bsum);
  k_scan3<<<(N_NODES+255)/256, 256, 0, stream>>>(rowptr, bsum, cursor);
  k_scatter_edges<<<(NNZ+255)/256, 256, 0, stream>>>(lrows, lcols, lvals, cursor, edges);

  // layer-0 slice (raw E0)
  k_gather_wave<<<(3*BATCH+3)/4, 256, 0, stream>>>(E0, u_id, pos, neg, out, 0, 0);

  // ---- layers (ping-pong E0 <-> E1) ----
  float* Ein = E0; float* Eout = E1;
  for (int i = 0; i < NL; i++){
    k_fused2<<<(N_NODES+63)/64, 256, 0, stream>>>(Ein, Eout, rowptr, edges,
                                                  Wt + i*EMB*160, biasf + i*EMB);
    k_gather_wave<<<(3*BATCH+3)/4, 256, 0, stream>>>(Eout, u_id, pos, neg, out, i+1, 1);
    float* t = Ein; Ein = Eout; Eout = t;
  }
}

// Round 6
// 586.478 us; speedup vs baseline: 1.5228x; 1.1142x over previous
//
#include <hip/hip_runtime.h>
#include <hip/hip_bf16.h>

#define N_USER 200000
#define N_ITEM 100000
#define N_NODES 300000
#define EMB 80
#define FEAT 16
#define NL 3
#define NNZ 1000000
#define BATCH 4096
#define OUTW 320

typedef __bf16 bf16x8 __attribute__((ext_vector_type(8)));
typedef float f32x4 __attribute__((ext_vector_type(4)));

__device__ __forceinline__ unsigned short f2bf(float f){
  union { float f; unsigned int i; } x; x.f = f;
  unsigned int i = x.i;
  unsigned int r = i + 0x7fff + ((i >> 16) & 1u);
  return (unsigned short)(r >> 16);
}
__device__ __forceinline__ float bf2f_lo(unsigned int u){   // low short -> float
  union { unsigned int i; float f; } x; x.i = u << 16; return x.f;
}
__device__ __forceinline__ float bf2f_hi(unsigned int u){   // high short -> float
  union { unsigned int i; float f; } x; x.i = u & 0xffff0000u; return x.f;
}

// ---- diagnostic fill ----
__global__ void k_fill(float* out, int n, float v){
  int i = blockIdx.x * blockDim.x + threadIdx.x;
  if (i < n) out[i] = v;
}

// ---- winner: last write wins for duplicate u_id ----
__global__ void k_winner(const int* __restrict__ u_id, int* __restrict__ winner){
  int b = blockIdx.x * blockDim.x + threadIdx.x;
  if (b >= BATCH) return;
  atomicMax(&winner[u_id[b]], b);
}

// ---- EB0 = bf16(concat(user_tab, item_tab)): float4 in -> 4 bf16 (uint2) out ----
__global__ void k_copy_bf(const float4* __restrict__ user_tab, const float4* __restrict__ item_tab,
                          uint2* __restrict__ EB){
  int idx = blockIdx.x * blockDim.x + threadIdx.x;
  if (idx >= N_NODES*EMB/4) return;
  float4 v = (idx < N_USER*EMB/4) ? user_tab[idx] : item_tab[idx - N_USER*EMB/4];
  uint2 o;
  o.x = (unsigned int)f2bf(v.x) | ((unsigned int)f2bf(v.y) << 16);
  o.y = (unsigned int)f2bf(v.z) | ((unsigned int)f2bf(v.w) << 16);
  EB[idx] = o;
}

// ---- blended scatter into bf16 E0 ----
__global__ void k_scatter_blend(const int* __restrict__ u_id, const int* __restrict__ winner,
                        const int* __restrict__ age, const int* __restrict__ sex,
                        const int* __restrict__ month, const int* __restrict__ day,
                        const int* __restrict__ dow,
                        const float* __restrict__ user_tab,
                        const float* __restrict__ age_tab, const float* __restrict__ sex_tab,
                        const float* __restrict__ month_tab, const float* __restrict__ day_tab,
                        const float* __restrict__ dow_tab,
                        unsigned short* __restrict__ EB){
  int idx = blockIdx.x * blockDim.x + threadIdx.x;
  if (idx >= BATCH*EMB) return;
  int b = idx / EMB;
  int c = idx - b*EMB;
  int u = u_id[b];
  if (winner[u] != b) return;
  int t = c >> 4, cc = c & 15;
  int key; const float* tab;
  switch (t){
    case 0: key = age[b];   tab = age_tab;   break;
    case 1: key = sex[b];   tab = sex_tab;   break;
    case 2: key = month[b]; tab = month_tab; break;
    case 3: key = day[b];   tab = day_tab;   break;
    default: key = dow[b];  tab = dow_tab;   break;
  }
  float f = tab[key*FEAT + cc];
  EB[(size_t)u*EMB + c] = f2bf(0.5f * user_tab[(size_t)u*EMB + c] + 0.5f * f);
}

// ---- prep: Wt[i][n][k] = stacked [W1;W2]^T (bf16, n-major), biasf = 2*b1+b2 ----
__global__ void k_prep(const float* __restrict__ W1, const float* __restrict__ W2,
                       const float* __restrict__ b1, const float* __restrict__ b2,
                       unsigned short* __restrict__ Wt, float* __restrict__ biasf){
  int idx = blockIdx.x * blockDim.x + threadIdx.x;
  if (idx < NL*EMB*160){
    int i = idx / (EMB*160);
    int rem = idx - i*(EMB*160);
    int n = rem / 160;
    int k = rem - n*160;
    float v = (k < EMB) ? W1[i*EMB*EMB + k*EMB + n] : W2[i*EMB*EMB + (k-EMB)*EMB + n];
    Wt[idx] = f2bf(v);
  } else if (idx < NL*EMB*160 + NL*EMB){
    int t = idx - NL*EMB*160;
    biasf[t] = 2.0f * b1[t] + b2[t];
  }
}

// ================= CSR build =================
__global__ void k_hist(const int* __restrict__ rows, int* __restrict__ cnt){
  int e = blockIdx.x * blockDim.x + threadIdx.x;
  if (e < NNZ) atomicAdd(&cnt[rows[e]], 1);
}

#define SCAN_BLK 1024
__global__ void k_scan1(int* __restrict__ cnt, int* __restrict__ bsum){
  __shared__ int s[256];
  int tid = threadIdx.x;
  int base = blockIdx.x * SCAN_BLK + tid*4;
  int v[4]; int sum = 0;
  #pragma unroll
  for (int j = 0; j < 4; j++){
    int i = base + j;
    v[j] = (i < N_NODES) ? cnt[i] : 0;
    sum += v[j];
  }
  s[tid] = sum; __syncthreads();
  int own = sum;
  for (int d = 1; d < 256; d <<= 1){
    int t = (tid >= d) ? s[tid-d] : 0;
    __syncthreads();
    s[tid] += t;
    __syncthreads();
  }
  int excl = s[tid] - own;
  if (tid == 0) bsum[blockIdx.x] = s[255];
  int run = excl;
  #pragma unroll
  for (int j = 0; j < 4; j++){
    int i = base + j;
    if (i < N_NODES) cnt[i] = run;
    run += v[j];
  }
}

#define NSCAN_BLOCKS ((N_NODES + SCAN_BLK - 1)/SCAN_BLK)   // 293
__global__ void k_scan2(int* __restrict__ bsum){
  __shared__ int s[512];
  int tid = threadIdx.x;
  int v = (tid < NSCAN_BLOCKS) ? bsum[tid] : 0;
  s[tid] = v; __syncthreads();
  for (int d = 1; d < 512; d <<= 1){
    int t = (tid >= d) ? s[tid-d] : 0;
    __syncthreads();
    s[tid] += t;
    __syncthreads();
  }
  if (tid < NSCAN_BLOCKS) bsum[tid] = s[tid] - v;
}

__global__ void k_scan3(int* __restrict__ rowptr, const int* __restrict__ bsum,
                        int* __restrict__ cursor){
  int i = blockIdx.x * blockDim.x + threadIdx.x;
  if (i >= N_NODES) return;
  int v = rowptr[i] + bsum[i >> 10];
  rowptr[i] = v;
  cursor[i] = v;
  if (i == 0) rowptr[N_NODES] = NNZ;
}

// edges[pos] = {col, bitcast(val)}
__global__ void k_scatter_edges(const int* __restrict__ rows, const int* __restrict__ cols,
                                const float* __restrict__ vals,
                                int* __restrict__ cursor,
                                int2* __restrict__ edges){
  int e = blockIdx.x * blockDim.x + threadIdx.x;
  if (e >= NNZ) return;
  int r = rows[e];
  int pos = atomicAdd(&cursor[r], 1);
  int2 ed; ed.x = cols[e]; ed.y = __float_as_int(vals[e]);
  edges[pos] = ed;
}

// ==== fused layer v7: bf16 E storage — halves gather bytes, E ping-pong L3-resident ====
#define LE_PAD 84   // floats; 336 B row stride (LDS accum stays fp32)
__launch_bounds__(256)
__global__ void k_fused2(const unsigned short* __restrict__ EBin, unsigned short* __restrict__ EBout,
                         const int* __restrict__ rowptr, const int2* __restrict__ edges,
                         const unsigned short* __restrict__ Wt, const float* __restrict__ biasf){
  __shared__ float le[64 * LE_PAD];   // 21504 B
  int tid = threadIdx.x;
  long row0 = (long)blockIdx.x * 64;

  int lane = tid & 63;
  int wave = tid >> 6;
  int m = lane & 15;
  int quad = lane >> 4;

  // phase 1: CSR SpMM rows -> LDS (fp32). Thread owns (row tid>>2, bf16 elems [qg*20, qg*20+20)).
  // Gathered rows are bf16: 160 B/row; per edge 5 x uint2 (8 B, aligned) per thread.
  {
    int lr = tid >> 2;
    int qg = tid & 3;
    long r = row0 + lr;
    int s = 0, e = 0;
    if (r < N_NODES){ s = rowptr[r]; e = rowptr[r+1]; }
    const unsigned short* eb = EBin + qg*20;
    f32x4 a[5];
    #pragma unroll
    for (int j = 0; j < 5; j++) a[j] = (f32x4){0.f,0.f,0.f,0.f};
    int ilast = e - 1;
    for (int i = s; i < e; i += 4){
      int rem = e - i;
      int2 ed0 = edges[i];
      int2 ed1 = edges[min(i+1, ilast)];
      int2 ed2 = edges[min(i+2, ilast)];
      int2 ed3 = edges[min(i+3, ilast)];
      float v0 = __int_as_float(ed0.y);
      float v1 = (rem > 1) ? __int_as_float(ed1.y) : 0.f;
      float v2 = (rem > 2) ? __int_as_float(ed2.y) : 0.f;
      float v3 = (rem > 3) ? __int_as_float(ed3.y) : 0.f;
      const unsigned short* g0 = eb + (size_t)ed0.x*EMB;
      const unsigned short* g1 = eb + (size_t)ed1.x*EMB;
      const unsigned short* g2 = eb + (size_t)ed2.x*EMB;
      const unsigned short* g3 = eb + (size_t)ed3.x*EMB;
      #pragma unroll
      for (int j = 0; j < 5; j++){
        uint2 u0 = *(const uint2*)(g0 + j*4);
        uint2 u1 = *(const uint2*)(g1 + j*4);
        uint2 u2 = *(const uint2*)(g2 + j*4);
        uint2 u3 = *(const uint2*)(g3 + j*4);
        a[j].x += v0*bf2f_lo(u0.x) + v1*bf2f_lo(u1.x) + v2*bf2f_lo(u2.x) + v3*bf2f_lo(u3.x);
        a[j].y += v0*bf2f_hi(u0.x) + v1*bf2f_hi(u1.x) + v2*bf2f_hi(u2.x) + v3*bf2f_hi(u3.x);
        a[j].z += v0*bf2f_lo(u0.y) + v1*bf2f_lo(u1.y) + v2*bf2f_lo(u2.y) + v3*bf2f_lo(u3.y);
        a[j].w += v0*bf2f_hi(u0.y) + v1*bf2f_hi(u1.y) + v2*bf2f_hi(u2.y) + v3*bf2f_hi(u3.y);
      }
    }
    float* lp = le + lr*LE_PAD + qg*20;
    #pragma unroll
    for (int j = 0; j < 5; j++) *(f32x4*)(lp + j*4) = a[j];
  }

  // B fragments (Wt n-major) — after phase 1; overlap the lgkm drain
  bf16x8 bfrag[5][5];
  #pragma unroll
  for (int nt = 0; nt < 5; nt++)
    #pragma unroll
    for (int kt = 0; kt < 5; kt++)
      bfrag[nt][kt] = *(const bf16x8*)(Wt + (nt*16 + m)*160 + kt*32 + quad*8);

  // wave-local phase boundary (wave w writes/reads only LDS rows 16w..16w+15)
  asm volatile("s_waitcnt lgkmcnt(0)" ::: "memory");
  __builtin_amdgcn_sched_barrier(0);

  // phase 2: K=160 GEMM, A-fragments in registers
  int arow = wave*16 + m;
  long rA = row0 + arow;
  const unsigned short* erow = EBin + (size_t)(rA < N_NODES ? rA : 0) * EMB;
  const float* lrow = le + arow*LE_PAD;

  f32x4 acc[5];
  #pragma unroll
  for (int nt = 0; nt < 5; nt++) acc[nt] = (f32x4){0.f,0.f,0.f,0.f};

  #pragma unroll
  for (int kt = 0; kt < 5; kt++){
    int k8 = kt*32 + quad*8;              // 8 consecutive k's; never crosses 80
    bool addh = (k8 < EMB);
    int c8 = addh ? k8 : k8 - EMB;
    uint4 eu = *(const uint4*)(erow + c8);    // 8 bf16, 16-B aligned (c8 mult of 8)
    float e0=bf2f_lo(eu.x), e1=bf2f_hi(eu.x), e2=bf2f_lo(eu.y), e3=bf2f_hi(eu.y);
    float e4=bf2f_lo(eu.z), e5=bf2f_hi(eu.z), e6=bf2f_lo(eu.w), e7=bf2f_hi(eu.w);
    float4 l0 = *(const float4*)(lrow + c8);
    float4 l1 = *(const float4*)(lrow + c8 + 4);
    float x0,x1,x2,x3,x4,x5,x6,x7;
    if (addh){
      x0=e0+l0.x; x1=e1+l0.y; x2=e2+l0.z; x3=e3+l0.w;
      x4=e4+l1.x; x5=e5+l1.y; x6=e6+l1.z; x7=e7+l1.w;
    } else {
      x0=e0*l0.x; x1=e1*l0.y; x2=e2*l0.z; x3=e3*l0.w;
      x4=e4*l1.x; x5=e5*l1.y; x6=e6*l1.z; x7=e7*l1.w;
    }
    bf16x8 af;
    af[0]=(__bf16)x0; af[1]=(__bf16)x1; af[2]=(__bf16)x2; af[3]=(__bf16)x3;
    af[4]=(__bf16)x4; af[5]=(__bf16)x5; af[6]=(__bf16)x6; af[7]=(__bf16)x7;
    #pragma unroll
    for (int nt = 0; nt < 5; nt++)
      acc[nt] = __builtin_amdgcn_mfma_f32_16x16x32_bf16(af, bfrag[nt][kt], acc[nt], 0, 0, 0);
  }

  // epilogue: leaky-relu, store bf16. C/D layout col=lane&15, row=quad*4+reg
  long rbase = row0 + wave*16 + quad*4;
  #pragma unroll
  for (int nt = 0; nt < 5; nt++){
    int col = nt*16 + m;
    float b = biasf[col];
    #pragma unroll
    for (int i = 0; i < 4; i++){
      long r = rbase + i;
      if (r < N_NODES){
        float v = acc[nt][i] + b;
        v = (v > 0.f) ? v : 0.2f * v;
        EBout[r*EMB + col] = f2bf(v);
      }
    }
  }
}

// ---- fused gather + row L2 norm (wave per gathered row), bf16 in, fp32 out ----
__global__ void k_gather_wave(const unsigned short* __restrict__ EB, const int* __restrict__ u_id,
                              const int* __restrict__ pos, const int* __restrict__ neg,
                              float* __restrict__ out, int layer, int do_norm){
  int gw = blockIdx.x * (blockDim.x >> 6) + (threadIdx.x >> 6);
  if (gw >= 3*BATCH) return;
  int lane = threadIdx.x & 63;
  int chunk = gw / BATCH;
  int b = gw - chunk*BATCH;
  int node = (chunk == 0) ? u_id[b] : ((chunk == 1) ? N_USER + pos[b] : N_USER + neg[b]);
  const unsigned short* er = EB + (size_t)node*EMB;
  union { unsigned int i; float f; } c0, c1;
  c0.i = (unsigned int)er[lane] << 16;
  float v0 = c0.f;
  float v1 = 0.f;
  if (lane < EMB-64){ c1.i = (unsigned int)er[64 + lane] << 16; v1 = c1.f; }
  float scale = 1.f;
  if (do_norm){
    float ss = v0*v0 + v1*v1;
    #pragma unroll
    for (int s = 32; s > 0; s >>= 1) ss += __shfl_xor(ss, s, 64);
    float nrm = fmaxf(sqrtf(ss), 1e-12f);
    scale = 1.f / nrm;
  }
  float* po = out + (size_t)chunk*BATCH*OUTW + (size_t)b*OUTW + layer*EMB;
  po[lane] = v0 * scale;
  if (lane < EMB-64) po[64 + lane] = v1 * scale;
}

extern "C" void kernel_launch(void* const* d_in, const int* in_sizes, int n_in,
                              void* d_out, int out_size, void* d_ws, size_t ws_size,
                              hipStream_t stream) {
  float* out = (float*)d_out;

  const size_t OFF_EB0    = 0;                   // 48,000,000 (bf16 E ping)
  const size_t OFF_EB1    = 48000000;            // 48,000,000 (bf16 E pong)
  const size_t OFF_ROWPTR = 96000000;            // 1,200,640
  const size_t OFF_CURSOR = 97200640;            // 1,200,640
  const size_t OFF_EDGES  = 98401280;            // 8,000,000 (int2 per edge)
  const size_t OFF_BSUM   = 106401280;           // 4,096
  const size_t OFF_WT     = 106405376;           // 76,800
  const size_t OFF_BIAS   = 106482176;           // 1,024
  const size_t OFF_WIN    = 106483200;           // 800,000
  const size_t NEED       = 107283200;

  float code = 0.f;
  if (ws_size < NEED)                      code = 7.f;
  else if (n_in != 22)                     code = 9.f;
  else if (in_sizes[0] != BATCH)           code = 11.f;
  else if (in_sizes[10] != NNZ)            code = 13.f;
  else if (out_size != 3*BATCH*OUTW)       code = 19.f;
  if (code != 0.f){
    k_fill<<<(out_size + 255)/256, 256, 0, stream>>>(out, out_size, code);
    return;
  }

  const int* u_id  = (const int*)d_in[0];
  const int* age   = (const int*)d_in[1];
  const int* sex   = (const int*)d_in[2];
  const int* month = (const int*)d_in[3];
  const int* day   = (const int*)d_in[4];
  const int* dow   = (const int*)d_in[5];
  const int* pos   = (const int*)d_in[6];
  const int* neg   = (const int*)d_in[7];
  const int* lrows = (const int*)d_in[8];
  const int* lcols = (const int*)d_in[9];
  const float* lvals    = (const float*)d_in[10];
  const float* user_tab = (const float*)d_in[11];
  const float* item_tab = (const float*)d_in[12];
  const float* age_tab  = (const float*)d_in[13];
  const float* sex_tab  = (const float*)d_in[14];
  const float* month_tab= (const float*)d_in[15];
  const float* day_tab  = (const float*)d_in[16];
  const float* dow_tab  = (const float*)d_in[17];
  const float* W1 = (const float*)d_in[18];
  const float* b1 = (const float*)d_in[19];
  const float* W2 = (const float*)d_in[20];
  const float* b2 = (const float*)d_in[21];

  char* ws = (char*)d_ws;
  unsigned short* EB0 = (unsigned short*)(ws + OFF_EB0);
  unsigned short* EB1 = (unsigned short*)(ws + OFF_EB1);
  int* rowptr   = (int*)(ws + OFF_ROWPTR);
  int* cursor   = (int*)(ws + OFF_CURSOR);
  int2* edges   = (int2*)(ws + OFF_EDGES);
  int* bsum     = (int*)(ws + OFF_BSUM);
  unsigned short* Wt = (unsigned short*)(ws + OFF_WT);
  float* biasf  = (float*)(ws + OFF_BIAS);
  int* winner   = (int*)(ws + OFF_WIN);

  // ---- prologue: build bf16 E0 ----
  hipMemsetAsync(winner, 0xFF, N_USER*sizeof(int), stream);
  k_winner<<<(BATCH+255)/256, 256, 0, stream>>>(u_id, winner);
  k_copy_bf<<<(N_NODES*EMB/4+255)/256, 256, 0, stream>>>((const float4*)user_tab, (const float4*)item_tab, (uint2*)EB0);
  k_scatter_blend<<<(BATCH*EMB+255)/256, 256, 0, stream>>>(u_id, winner, age, sex, month, day, dow,
                                                   user_tab, age_tab, sex_tab, month_tab,
                                                   day_tab, dow_tab, EB0);
  k_prep<<<(NL*EMB*160 + NL*EMB + 255)/256, 256, 0, stream>>>(W1, W2, b1, b2, Wt, biasf);

  // ---- CSR build ----
  hipMemsetAsync(rowptr, 0, (N_NODES+1)*sizeof(int), stream);
  k_hist<<<(NNZ+255)/256, 256, 0, stream>>>(lrows, rowptr);
  k_scan1<<<NSCAN_BLOCKS, 256, 0, stream>>>(rowptr, bsum);
  k_scan2<<<1, 512, 0, stream>>>(bsum);
  k_scan3<<<(N_NODES+255)/256, 256, 0, stream>>>(rowptr, bsum, cursor);
  k_scatter_edges<<<(NNZ+255)/256, 256, 0, stream>>>(lrows, lcols, lvals, cursor, edges);

  // layer-0 slice (raw E0)
  k_gather_wave<<<(3*BATCH+3)/4, 256, 0, stream>>>(EB0, u_id, pos, neg, out, 0, 0);

  // ---- layers (ping-pong EB0 <-> EB1) ----
  unsigned short* Ein = EB0; unsigned short* Eout = EB1;
  for (int i = 0; i < NL; i++){
    k_fused2<<<(N_NODES+63)/64, 256, 0, stream>>>(Ein, Eout, rowptr, edges,
                                                  Wt + i*EMB*160, biasf + i*EMB);
    k_gather_wave<<<(3*BATCH+3)/4, 256, 0, stream>>>(Eout, u_id, pos, neg, out, i+1, 1);
    unsigned short* t = Ein; Ein = Eout; Eout = t;
  }
}

// Round 8
// 579.960 us; speedup vs baseline: 1.5399x; 1.0112x over previous
//
#include <hip/hip_runtime.h>
#include <hip/hip_bf16.h>

#define N_USER 200000
#define N_ITEM 100000
#define N_NODES 300000
#define EMB 80
#define FEAT 16
#define NL 3
#define NNZ 1000000
#define BATCH 4096
#define OUTW 320

typedef __bf16 bf16x8 __attribute__((ext_vector_type(8)));
typedef float f32x4 __attribute__((ext_vector_type(4)));

__device__ __forceinline__ unsigned short f2bf(float f){
  union { float f; unsigned int i; } x; x.f = f;
  unsigned int i = x.i;
  unsigned int r = i + 0x7fff + ((i >> 16) & 1u);
  return (unsigned short)(r >> 16);
}
__device__ __forceinline__ float bf2f_lo(unsigned int u){   // low short -> float
  union { unsigned int i; float f; } x; x.i = u << 16; return x.f;
}
__device__ __forceinline__ float bf2f_hi(unsigned int u){   // high short -> float
  union { unsigned int i; float f; } x; x.i = u & 0xffff0000u; return x.f;
}

// accumulate 8 bf16 (uint4) * v into a[0..1] (f32x4 pair)
__device__ __forceinline__ void acc8(f32x4* a, uint4 u, float v){
  a[0].x += v*bf2f_lo(u.x); a[0].y += v*bf2f_hi(u.x);
  a[0].z += v*bf2f_lo(u.y); a[0].w += v*bf2f_hi(u.y);
  a[1].x += v*bf2f_lo(u.z); a[1].y += v*bf2f_hi(u.z);
  a[1].z += v*bf2f_lo(u.w); a[1].w += v*bf2f_hi(u.w);
}

// combine L_E (fp32) with own E chunk (bf16 uint4): write bf16 add-half & mul-half to LDS
__device__ __forceinline__ void combine_store(unsigned short* lp_add, unsigned short* lp_mul,
                                              const f32x4* a, uint4 u){
  float e0=bf2f_lo(u.x), e1=bf2f_hi(u.x), e2=bf2f_lo(u.y), e3=bf2f_hi(u.y);
  float e4=bf2f_lo(u.z), e5=bf2f_hi(u.z), e6=bf2f_lo(u.w), e7=bf2f_hi(u.w);
  bf16x8 av, mv;
  av[0]=(__bf16)(a[0].x+e0); av[1]=(__bf16)(a[0].y+e1);
  av[2]=(__bf16)(a[0].z+e2); av[3]=(__bf16)(a[0].w+e3);
  av[4]=(__bf16)(a[1].x+e4); av[5]=(__bf16)(a[1].y+e5);
  av[6]=(__bf16)(a[1].z+e6); av[7]=(__bf16)(a[1].w+e7);
  mv[0]=(__bf16)(a[0].x*e0); mv[1]=(__bf16)(a[0].y*e1);
  mv[2]=(__bf16)(a[0].z*e2); mv[3]=(__bf16)(a[0].w*e3);
  mv[4]=(__bf16)(a[1].x*e4); mv[5]=(__bf16)(a[1].y*e5);
  mv[6]=(__bf16)(a[1].z*e6); mv[7]=(__bf16)(a[1].w*e7);
  *(bf16x8*)lp_add = av;
  *(bf16x8*)lp_mul = mv;
}

// ---- diagnostic fill ----
__global__ void k_fill(float* out, int n, float v){
  int i = blockIdx.x * blockDim.x + threadIdx.x;
  if (i < n) out[i] = v;
}

// ---- winner: last write wins for duplicate u_id ----
__global__ void k_winner(const int* __restrict__ u_id, int* __restrict__ winner){
  int b = blockIdx.x * blockDim.x + threadIdx.x;
  if (b >= BATCH) return;
  atomicMax(&winner[u_id[b]], b);
}

// ---- EB0 = bf16(concat(user_tab, item_tab)): float4 in -> 4 bf16 (uint2) out ----
__global__ void k_copy_bf(const float4* __restrict__ user_tab, const float4* __restrict__ item_tab,
                          uint2* __restrict__ EB){
  int idx = blockIdx.x * blockDim.x + threadIdx.x;
  if (idx >= N_NODES*EMB/4) return;
  float4 v = (idx < N_USER*EMB/4) ? user_tab[idx] : item_tab[idx - N_USER*EMB/4];
  uint2 o;
  o.x = (unsigned int)f2bf(v.x) | ((unsigned int)f2bf(v.y) << 16);
  o.y = (unsigned int)f2bf(v.z) | ((unsigned int)f2bf(v.w) << 16);
  EB[idx] = o;
}

// ---- blended scatter into bf16 E0 ----
__global__ void k_scatter_blend(const int* __restrict__ u_id, const int* __restrict__ winner,
                        const int* __restrict__ age, const int* __restrict__ sex,
                        const int* __restrict__ month, const int* __restrict__ day,
                        const int* __restrict__ dow,
                        const float* __restrict__ user_tab,
                        const float* __restrict__ age_tab, const float* __restrict__ sex_tab,
                        const float* __restrict__ month_tab, const float* __restrict__ day_tab,
                        const float* __restrict__ dow_tab,
                        unsigned short* __restrict__ EB){
  int idx = blockIdx.x * blockDim.x + threadIdx.x;
  if (idx >= BATCH*EMB) return;
  int b = idx / EMB;
  int c = idx - b*EMB;
  int u = u_id[b];
  if (winner[u] != b) return;
  int t = c >> 4, cc = c & 15;
  int key; const float* tab;
  switch (t){
    case 0: key = age[b];   tab = age_tab;   break;
    case 1: key = sex[b];   tab = sex_tab;   break;
    case 2: key = month[b]; tab = month_tab; break;
    case 3: key = day[b];   tab = day_tab;   break;
    default: key = dow[b];  tab = dow_tab;   break;
  }
  float f = tab[key*FEAT + cc];
  EB[(size_t)u*EMB + c] = f2bf(0.5f * user_tab[(size_t)u*EMB + c] + 0.5f * f);
}

// ---- prep: Wt[i][n][k] = stacked [W1;W2]^T (bf16, n-major), biasf = 2*b1+b2 ----
__global__ void k_prep(const float* __restrict__ W1, const float* __restrict__ W2,
                       const float* __restrict__ b1, const float* __restrict__ b2,
                       unsigned short* __restrict__ Wt, float* __restrict__ biasf){
  int idx = blockIdx.x * blockDim.x + threadIdx.x;
  if (idx < NL*EMB*160){
    int i = idx / (EMB*160);
    int rem = idx - i*(EMB*160);
    int n = rem / 160;
    int k = rem - n*160;
    float v = (k < EMB) ? W1[i*EMB*EMB + k*EMB + n] : W2[i*EMB*EMB + (k-EMB)*EMB + n];
    Wt[idx] = f2bf(v);
  } else if (idx < NL*EMB*160 + NL*EMB){
    int t = idx - NL*EMB*160;
    biasf[t] = 2.0f * b1[t] + b2[t];
  }
}

// ================= CSR build =================
__global__ void k_hist(const int* __restrict__ rows, int* __restrict__ cnt){
  int e = blockIdx.x * blockDim.x + threadIdx.x;
  if (e < NNZ) atomicAdd(&cnt[rows[e]], 1);
}

#define SCAN_BLK 1024
__global__ void k_scan1(int* __restrict__ cnt, int* __restrict__ bsum){
  __shared__ int s[256];
  int tid = threadIdx.x;
  int base = blockIdx.x * SCAN_BLK + tid*4;
  int v[4]; int sum = 0;
  #pragma unroll
  for (int j = 0; j < 4; j++){
    int i = base + j;
    v[j] = (i < N_NODES) ? cnt[i] : 0;
    sum += v[j];
  }
  s[tid] = sum; __syncthreads();
  int own = sum;
  for (int d = 1; d < 256; d <<= 1){
    int t = (tid >= d) ? s[tid-d] : 0;
    __syncthreads();
    s[tid] += t;
    __syncthreads();
  }
  int excl = s[tid] - own;
  if (tid == 0) bsum[blockIdx.x] = s[255];
  int run = excl;
  #pragma unroll
  for (int j = 0; j < 4; j++){
    int i = base + j;
    if (i < N_NODES) cnt[i] = run;
    run += v[j];
  }
}

#define NSCAN_BLOCKS ((N_NODES + SCAN_BLK - 1)/SCAN_BLK)   // 293
__global__ void k_scan2(int* __restrict__ bsum){
  __shared__ int s[512];
  int tid = threadIdx.x;
  int v = (tid < NSCAN_BLOCKS) ? bsum[tid] : 0;
  s[tid] = v; __syncthreads();
  for (int d = 1; d < 512; d <<= 1){
    int t = (tid >= d) ? s[tid-d] : 0;
    __syncthreads();
    s[tid] += t;
    __syncthreads();
  }
  if (tid < NSCAN_BLOCKS) bsum[tid] = s[tid] - v;
}

__global__ void k_scan3(int* __restrict__ rowptr, const int* __restrict__ bsum,
                        int* __restrict__ cursor){
  int i = blockIdx.x * blockDim.x + threadIdx.x;
  if (i >= N_NODES) return;
  int v = rowptr[i] + bsum[i >> 10];
  rowptr[i] = v;
  cursor[i] = v;
  if (i == 0) rowptr[N_NODES] = NNZ;
}

// edges[pos] = {col, bitcast(val)}
__global__ void k_scatter_edges(const int* __restrict__ rows, const int* __restrict__ cols,
                                const float* __restrict__ vals,
                                int* __restrict__ cursor,
                                int2* __restrict__ edges){
  int e = blockIdx.x * blockDim.x + threadIdx.x;
  if (e >= NNZ) return;
  int r = rows[e];
  int pos = atomicAdd(&cursor[r], 1);
  int2 ed; ed.x = cols[e]; ed.y = __float_as_int(vals[e]);
  edges[pos] = ed;
}

// ==== fused layer v9: phase 1 builds full bf16 A-row [(LE+E)|(LE*E)] in LDS;
//      phase 2 = pure ds_read_b128 + MFMA. uint4 interleaved-chunk gathers.
#define LE_STRIDE 168   // ushorts per LDS row = 336 B (16B-aligned, ~2-way banks)
__launch_bounds__(256)
__global__ void k_fused2(const unsigned short* __restrict__ EBin, unsigned short* __restrict__ EBout,
                         const int* __restrict__ rowptr, const int2* __restrict__ edges,
                         const unsigned short* __restrict__ Wt, const float* __restrict__ biasf){
  __shared__ unsigned short la[64 * LE_STRIDE];   // 21504 B
  int tid = threadIdx.x;
  long row0 = (long)blockIdx.x * 64;

  int lane = tid & 63;
  int wave = tid >> 6;
  int m = lane & 15;
  int quad = lane >> 4;

  // phase 1: thread owns (row tid>>2, chunks {qg, 4+qg, 8+qg(qg<2)} of 8 elems).
  {
    int lr = tid >> 2;
    int qg = tid & 3;
    long r = row0 + lr;
    int s = 0, e = 0;
    if (r < N_NODES){ s = rowptr[r]; e = rowptr[r+1]; }
    int eo = 8*qg;                       // elem offset of chunk within its 32-elem group
    f32x4 c0[2], c1[2], c2[2];
    c0[0]=(f32x4){0,0,0,0}; c0[1]=(f32x4){0,0,0,0};
    c1[0]=(f32x4){0,0,0,0}; c1[1]=(f32x4){0,0,0,0};
    c2[0]=(f32x4){0,0,0,0}; c2[1]=(f32x4){0,0,0,0};
    int ilast = e - 1;
    for (int i = s; i < e; i += 4){
      int rem = e - i;
      int2 ed0 = edges[i];
      int2 ed1 = edges[min(i+1, ilast)];
      int2 ed2 = edges[min(i+2, ilast)];
      int2 ed3 = edges[min(i+3, ilast)];
      float v0 = __int_as_float(ed0.y);
      float v1 = (rem > 1) ? __int_as_float(ed1.y) : 0.f;
      float v2 = (rem > 2) ? __int_as_float(ed2.y) : 0.f;
      float v3 = (rem > 3) ? __int_as_float(ed3.y) : 0.f;
      const unsigned short* g0 = EBin + (size_t)ed0.x*EMB + eo;
      const unsigned short* g1 = EBin + (size_t)ed1.x*EMB + eo;
      const unsigned short* g2 = EBin + (size_t)ed2.x*EMB + eo;
      const unsigned short* g3 = EBin + (size_t)ed3.x*EMB + eo;
      {
        uint4 u0 = *(const uint4*)(g0);
        uint4 u1 = *(const uint4*)(g1);
        uint4 u2 = *(const uint4*)(g2);
        uint4 u3 = *(const uint4*)(g3);
        acc8(c0, u0, v0); acc8(c0, u1, v1); acc8(c0, u2, v2); acc8(c0, u3, v3);
      }
      {
        uint4 u0 = *(const uint4*)(g0 + 32);
        uint4 u1 = *(const uint4*)(g1 + 32);
        uint4 u2 = *(const uint4*)(g2 + 32);
        uint4 u3 = *(const uint4*)(g3 + 32);
        acc8(c1, u0, v0); acc8(c1, u1, v1); acc8(c1, u2, v2); acc8(c1, u3, v3);
      }
      if (qg < 2){
        uint4 u0 = *(const uint4*)(g0 + 64);
        uint4 u1 = *(const uint4*)(g1 + 64);
        uint4 u2 = *(const uint4*)(g2 + 64);
        uint4 u3 = *(const uint4*)(g3 + 64);
        acc8(c2, u0, v0); acc8(c2, u1, v1); acc8(c2, u2, v2); acc8(c2, u3, v3);
      }
    }
    // combine with own E row -> packed bf16 A-row [add(0..79) | mul(80..159)]
    const unsigned short* myrow = EBin + (size_t)(r < N_NODES ? r : 0) * EMB;
    unsigned short* lp = la + lr*LE_STRIDE;
    {
      uint4 u = *(const uint4*)(myrow + eo);
      combine_store(lp + eo, lp + 80 + eo, c0, u);
    }
    {
      uint4 u = *(const uint4*)(myrow + 32 + eo);
      combine_store(lp + 32 + eo, lp + 80 + 32 + eo, c1, u);
    }
    if (qg < 2){
      uint4 u = *(const uint4*)(myrow + 64 + eo);
      combine_store(lp + 64 + eo, lp + 80 + 64 + eo, c2, u);
    }
  }

  // B fragments (Wt n-major) — global loads overlap the LDS drain
  bf16x8 bfrag[5][5];
  #pragma unroll
  for (int nt = 0; nt < 5; nt++)
    #pragma unroll
    for (int kt = 0; kt < 5; kt++)
      bfrag[nt][kt] = *(const bf16x8*)(Wt + (nt*16 + m)*160 + kt*32 + quad*8);

  // wave-local phase boundary (wave w writes/reads only LDS rows 16w..16w+15)
  asm volatile("s_waitcnt lgkmcnt(0)" ::: "memory");
  __builtin_amdgcn_sched_barrier(0);

  // phase 2: pure LDS A-fragment reads + MFMA
  int arow = wave*16 + m;
  const unsigned short* lA = la + arow*LE_STRIDE;

  f32x4 acc[5];
  #pragma unroll
  for (int nt = 0; nt < 5; nt++) acc[nt] = (f32x4){0.f,0.f,0.f,0.f};

  #pragma unroll
  for (int kt = 0; kt < 5; kt++){
    bf16x8 af = *(const bf16x8*)(lA + kt*32 + quad*8);
    #pragma unroll
    for (int nt = 0; nt < 5; nt++)
      acc[nt] = __builtin_amdgcn_mfma_f32_16x16x32_bf16(af, bfrag[nt][kt], acc[nt], 0, 0, 0);
  }

  // epilogue: leaky-relu, store bf16. C/D layout col=lane&15, row=quad*4+reg
  long rbase = row0 + wave*16 + quad*4;
  #pragma unroll
  for (int nt = 0; nt < 5; nt++){
    int col = nt*16 + m;
    float b = biasf[col];
    #pragma unroll
    for (int i = 0; i < 4; i++){
      long r = rbase + i;
      if (r < N_NODES){
        float v = acc[nt][i] + b;
        v = (v > 0.f) ? v : 0.2f * v;
        EBout[r*EMB + col] = f2bf(v);
      }
    }
  }
}

// ---- fused gather + row L2 norm (wave per gathered row), bf16 in, fp32 out ----
__global__ void k_gather_wave(const unsigned short* __restrict__ EB, const int* __restrict__ u_id,
                              const int* __restrict__ pos, const int* __restrict__ neg,
                              float* __restrict__ out, int layer, int do_norm){
  int gw = blockIdx.x * (blockDim.x >> 6) + (threadIdx.x >> 6);
  if (gw >= 3*BATCH) return;
  int lane = threadIdx.x & 63;
  int chunk = gw / BATCH;
  int b = gw - chunk*BATCH;
  int node = (chunk == 0) ? u_id[b] : ((chunk == 1) ? N_USER + pos[b] : N_USER + neg[b]);
  const unsigned short* er = EB + (size_t)node*EMB;
  union { unsigned int i; float f; } c0, c1;
  c0.i = (unsigned int)er[lane] << 16;
  float v0 = c0.f;
  float v1 = 0.f;
  if (lane < EMB-64){ c1.i = (unsigned int)er[64 + lane] << 16; v1 = c1.f; }
  float scale = 1.f;
  if (do_norm){
    float ss = v0*v0 + v1*v1;
    #pragma unroll
    for (int s = 32; s > 0; s >>= 1) ss += __shfl_xor(ss, s, 64);
    float nrm = fmaxf(sqrtf(ss), 1e-12f);
    scale = 1.f / nrm;
  }
  float* po = out + (size_t)chunk*BATCH*OUTW + (size_t)b*OUTW + layer*EMB;
  po[lane] = v0 * scale;
  if (lane < EMB-64) po[64 + lane] = v1 * scale;
}

extern "C" void kernel_launch(void* const* d_in, const int* in_sizes, int n_in,
                              void* d_out, int out_size, void* d_ws, size_t ws_size,
                              hipStream_t stream) {
  float* out = (float*)d_out;

  const size_t OFF_EB0    = 0;                   // 48,000,000 (bf16 E ping)
  const size_t OFF_EB1    = 48000000;            // 48,000,000 (bf16 E pong)
  const size_t OFF_ROWPTR = 96000000;            // 1,200,640
  const size_t OFF_CURSOR = 97200640;            // 1,200,640
  const size_t OFF_EDGES  = 98401280;            // 8,000,000 (int2 per edge)
  const size_t OFF_BSUM   = 106401280;           // 4,096
  const size_t OFF_WT     = 106405376;           // 76,800
  const size_t OFF_BIAS   = 106482176;           // 1,024
  const size_t OFF_WIN    = 106483200;           // 800,000
  const size_t NEED       = 107283200;

  float code = 0.f;
  if (ws_size < NEED)                      code = 7.f;
  else if (n_in != 22)                     code = 9.f;
  else if (in_sizes[0] != BATCH)           code = 11.f;
  else if (in_sizes[10] != NNZ)            code = 13.f;
  else if (out_size != 3*BATCH*OUTW)       code = 19.f;
  if (code != 0.f){
    k_fill<<<(out_size + 255)/256, 256, 0, stream>>>(out, out_size, code);
    return;
  }

  const int* u_id  = (const int*)d_in[0];
  const int* age   = (const int*)d_in[1];
  const int* sex   = (const int*)d_in[2];
  const int* month = (const int*)d_in[3];
  const int* day   = (const int*)d_in[4];
  const int* dow   = (const int*)d_in[5];
  const int* pos   = (const int*)d_in[6];
  const int* neg   = (const int*)d_in[7];
  const int* lrows = (const int*)d_in[8];
  const int* lcols = (const int*)d_in[9];
  const float* lvals    = (const float*)d_in[10];
  const float* user_tab = (const float*)d_in[11];
  const float* item_tab = (const float*)d_in[12];
  const float* age_tab  = (const float*)d_in[13];
  const float* sex_tab  = (const float*)d_in[14];
  const float* month_tab= (const float*)d_in[15];
  const float* day_tab  = (const float*)d_in[16];
  const float* dow_tab  = (const float*)d_in[17];
  const float* W1 = (const float*)d_in[18];
  const float* b1 = (const float*)d_in[19];
  const float* W2 = (const float*)d_in[20];
  const float* b2 = (const float*)d_in[21];

  char* ws = (char*)d_ws;
  unsigned short* EB0 = (unsigned short*)(ws + OFF_EB0);
  unsigned short* EB1 = (unsigned short*)(ws + OFF_EB1);
  int* rowptr   = (int*)(ws + OFF_ROWPTR);
  int* cursor   = (int*)(ws + OFF_CURSOR);
  int2* edges   = (int2*)(ws + OFF_EDGES);
  int* bsum     = (int*)(ws + OFF_BSUM);
  unsigned short* Wt = (unsigned short*)(ws + OFF_WT);
  float* biasf  = (float*)(ws + OFF_BIAS);
  int* winner   = (int*)(ws + OFF_WIN);

  // ---- prologue: build bf16 E0 ----
  hipMemsetAsync(winner, 0xFF, N_USER*sizeof(int), stream);
  k_winner<<<(BATCH+255)/256, 256, 0, stream>>>(u_id, winner);
  k_copy_bf<<<(N_NODES*EMB/4+255)/256, 256, 0, stream>>>((const float4*)user_tab, (const float4*)item_tab, (uint2*)EB0);
  k_scatter_blend<<<(BATCH*EMB+255)/256, 256, 0, stream>>>(u_id, winner, age, sex, month, day, dow,
                                                   user_tab, age_tab, sex_tab, month_tab,
                                                   day_tab, dow_tab, EB0);
  k_prep<<<(NL*EMB*160 + NL*EMB + 255)/256, 256, 0, stream>>>(W1, W2, b1, b2, Wt, biasf);

  // ---- CSR build ----
  hipMemsetAsync(rowptr, 0, (N_NODES+1)*sizeof(int), stream);
  k_hist<<<(NNZ+255)/256, 256, 0, stream>>>(lrows, rowptr);
  k_scan1<<<NSCAN_BLOCKS, 256, 0, stream>>>(rowptr, bsum);
  k_scan2<<<1, 512, 0, stream>>>(bsum);
  k_scan3<<<(N_NODES+255)/256, 256, 0, stream>>>(rowptr, bsum, cursor);
  k_scatter_edges<<<(NNZ+255)/256, 256, 0, stream>>>(lrows, lcols, lvals, cursor, edges);

  // layer-0 slice (raw E0)
  k_gather_wave<<<(3*BATCH+3)/4, 256, 0, stream>>>(EB0, u_id, pos, neg, out, 0, 0);

  // ---- layers (ping-pong EB0 <-> EB1) ----
  unsigned short* Ein = EB0; unsigned short* Eout = EB1;
  for (int i = 0; i < NL; i++){
    k_fused2<<<(N_NODES+63)/64, 256, 0, stream>>>(Ein, Eout, rowptr, edges,
                                                  Wt + i*EMB*160, biasf + i*EMB);
    k_gather_wave<<<(3*BATCH+3)/4, 256, 0, stream>>>(Eout, u_id, pos, neg, out, i+1, 1);
    unsigned short* t = Ein; Ein = Eout; Eout = t;
  }
}